// Round 9
// baseline (190.138 us; speedup 1.0000x reference)
//
#include <hip/hip_runtime.h>
#include <stdint.h>

typedef __bf16 bf16x8  __attribute__((ext_vector_type(8)));
typedef float  f32x4   __attribute__((ext_vector_type(4)));

#define LOG2E    1.44269504088896340736f
#define SM_SCALE 0.03125f   /* 1/sqrt(1024) */

typedef __attribute__((address_space(1))) const uint32_t gau32;
typedef __attribute__((address_space(3))) uint32_t       lau32;
#define GLD16(g, l) __builtin_amdgcn_global_load_lds((gau32*)(g), (lau32*)(l), 16, 0, 0)

__device__ __forceinline__ uint32_t f2bf(float f) {
  uint32_t u = __builtin_bit_cast(uint32_t, f);
  u += 0x7FFFu + ((u >> 16) & 1u);   // RNE
  return u >> 16;
}
__device__ __forceinline__ uint32_t pk2(float a, float b) {
  return f2bf(a) | (f2bf(b) << 16);
}
__device__ __forceinline__ uint4 pack8(float4 a, float4 b) {
  uint4 r;
  r.x = pk2(a.x, a.y); r.y = pk2(a.z, a.w);
  r.z = pk2(b.x, b.y); r.w = pk2(b.z, b.w);
  return r;
}

// ================= combined prepass (verified r7/r8; at HBM roofline) =================
// vt [prob][1024 d][512 key] bf16 ; xf [prob][ktile][dchunk32][lane][16B] fragment-major
__global__ __launch_bounds__(256)
void prep_comb(const float* __restrict__ x, uint16_t* __restrict__ vt,
               uint16_t* __restrict__ xf) {
  __shared__ char tl[64 * 144];
  const int t    = threadIdx.x;
  const int blk  = blockIdx.x;
  const int dc   = blk & 15;          // 64-d chunk
  const int kb   = (blk >> 4) & 7;    // 64-key chunk
  const int prob = blk >> 7;          // 0..63
  const int b  = prob >> 4, off = (prob >> 2) & 3, gs = prob & 3;

  const int key = t >> 2, dq = t & 3;
  const float* src = x + ((size_t)(b * 8192 + gs * 2048 + (kb * 64 + key) * 4 + off)) * 1024
                     + dc * 64 + dq * 16;
  float4 f0 = *(const float4*)(src);
  float4 f1 = *(const float4*)(src + 4);
  float4 f2 = *(const float4*)(src + 8);
  float4 f3 = *(const float4*)(src + 12);
  const int swz = (key & 7) << 4;
  *(uint4*)(tl + key * 144 + ((dq * 32) ^ swz))      = pack8(f0, f1);
  *(uint4*)(tl + key * 144 + ((dq * 32 + 16) ^ swz)) = pack8(f2, f3);
  __syncthreads();
  // vt (transposed)
  {
    const int d = t >> 2, kq = t & 3;
    uint32_t w[8];
#pragma unroll
    for (int i = 0; i < 8; ++i) {
      int k0 = kq * 16 + 2 * i, k1 = k0 + 1;
      uint32_t a  = *(const uint16_t*)(tl + k0 * 144 + ((2 * d) ^ ((k0 & 7) << 4)));
      uint32_t bb = *(const uint16_t*)(tl + k1 * 144 + ((2 * d) ^ ((k1 & 7) << 4)));
      w[i] = a | (bb << 16);
    }
    uint16_t* dst = vt + ((size_t)(prob * 1024 + dc * 64 + d)) * 512 + kb * 64 + kq * 16;
    *(uint4*)(dst)     = *(uint4*)&w[0];
    *(uint4*)(dst + 8) = *(uint4*)&w[4];
  }
  // xf (fragment-major)
  {
    const int row = t >> 2, p = t & 3;
    const int dcl = p >> 1;
    const int dq8b = (p & 1) * 2;
    const int swz2 = (row & 7) << 4;
    char* fbase = (char*)xf +
        (((size_t)(prob * 32 + kb * 4 + (row >> 4)) * 32) + (dc * 2 + dcl)) * 1024;
#pragma unroll
    for (int i = 0; i < 2; ++i) {
      const int dq8 = dq8b + i;
      uint4 w = *(const uint4*)(tl + row * 144 + ((dcl * 64 + dq8 * 16) ^ swz2));
      *(uint4*)(fbase + ((row & 15) + 16 * dq8) * 16) = w;
    }
  }
}

// ================= main kernel v7: r7 + B-prefetch + fragment-major P =================
// LDS: Q-frags [0,131072): [half][dcl][qt][1024B]; red0 @131072; red1 @135168
// P' fragment-major [qt][ks][lane][16B] = 64KB aliases [0,65536)
#define R6_0 131072
#define R6_1 135168
#define LDS6_BYTES 139264

#define LOADA6(dc, A0, A1) do {                                  \
    A0 = *(const bf16x8*)(xfA0 + (dc) * 1024);                   \
    A1 = *(const bf16x8*)(xfA1 + (dc) * 1024); } while (0)

#define LOADB6(dc, B) do {                                                        \
    const char* qb_ = smem + ((dc) >> 4) * 65536 + ((dc) & 15) * 4096 + lane16;   \
    B[0] = *(const bf16x8*)(qb_);                                                 \
    B[1] = *(const bf16x8*)(qb_ + 1024);                                          \
    B[2] = *(const bf16x8*)(qb_ + 2048);                                          \
    B[3] = *(const bf16x8*)(qb_ + 3072); } while (0)

#define MFMA8(A0, A1, B) do {                                                     \
    S[0][0] = __builtin_amdgcn_mfma_f32_16x16x32_bf16(A0, B[0], S[0][0], 0, 0, 0);\
    S[0][1] = __builtin_amdgcn_mfma_f32_16x16x32_bf16(A0, B[1], S[0][1], 0, 0, 0);\
    S[0][2] = __builtin_amdgcn_mfma_f32_16x16x32_bf16(A0, B[2], S[0][2], 0, 0, 0);\
    S[0][3] = __builtin_amdgcn_mfma_f32_16x16x32_bf16(A0, B[3], S[0][3], 0, 0, 0);\
    S[1][0] = __builtin_amdgcn_mfma_f32_16x16x32_bf16(A1, B[0], S[1][0], 0, 0, 0);\
    S[1][1] = __builtin_amdgcn_mfma_f32_16x16x32_bf16(A1, B[1], S[1][1], 0, 0, 0);\
    S[1][2] = __builtin_amdgcn_mfma_f32_16x16x32_bf16(A1, B[2], S[1][2], 0, 0, 0);\
    S[1][3] = __builtin_amdgcn_mfma_f32_16x16x32_bf16(A1, B[3], S[1][3], 0, 0, 0);\
  } while (0)

__global__ __launch_bounds__(1024, 4)
void dilattn6(const char* __restrict__ xf, const char* __restrict__ vt,
              float* __restrict__ out) {
  extern __shared__ char smem[];

  const int tid  = threadIdx.x;
  const int lane = tid & 63;
  const int wid  = tid >> 6;          // 0..15
  const int h    = lane >> 4;
  const int l15  = lane & 15;
  const int lane16 = lane * 16;

  const int blk  = blockIdx.x;        // bijective XCD map
  const int prob = ((blk & 7) << 3) | (blk >> 6);
  const int q0   = ((blk >> 3) & 7) * 64;
  const int b    = prob >> 4;
  const int off  = (prob >> 2) & 3;
  const int gs   = prob & 3;

  const char* xfp = xf + (size_t)prob * 1048576;
  const int qtile0 = q0 >> 4;

  // ---- stage ALL Q-frags (128 KB) via global_load_lds ----
#pragma unroll
  for (int half = 0; half < 2; ++half)
#pragma unroll
    for (int i = 0; i < 4; ++i) {
      const int c = wid * 4 + i;            // cell: dcl = c>>2, qt = c&3
      const int dcl = c >> 2, qt = c & 3;
      const char* src = xfp + ((size_t)(qtile0 + qt) * 32 + (half * 16 + dcl)) * 1024 + lane16;
      GLD16(src, smem + half * 65536 + dcl * 4096 + qt * 1024);
    }

  const char* xfA0 = xfp + (size_t)(2 * wid) * 32768 + lane16;
  const char* xfA1 = xfA0 + 32768;

  f32x4 S[2][4];
#pragma unroll
  for (int i = 0; i < 2; ++i)
#pragma unroll
    for (int j = 0; j < 4; ++j) S[i][j] = (f32x4){0.f, 0.f, 0.f, 0.f};

  bf16x8 aP0, aP1, aQ0, aQ1, bA[4], bB[4];
  LOADA6(0, aP0, aP1);
  LOADA6(1, aQ0, aQ1);
  __syncthreads();                         // Q staged
  LOADB6(0, bA);
  LOADB6(1, bB);

  // ===== phase 1: S = K Q^T over 32 d-chunks; A and B both depth-2 =====
#pragma unroll
  for (int dc2 = 0; dc2 < 32; dc2 += 2) {
    __builtin_amdgcn_s_setprio(1);
    MFMA8(aP0, aP1, bA);
    __builtin_amdgcn_s_setprio(0);
    if (dc2 + 2 < 32) { LOADA6(dc2 + 2, aP0, aP1); LOADB6(dc2 + 2, bA); }
    __builtin_amdgcn_s_setprio(1);
    MFMA8(aQ0, aQ1, bB);
    __builtin_amdgcn_s_setprio(0);
    if (dc2 + 3 < 32) { LOADA6(dc2 + 3, aQ0, aQ1); LOADB6(dc2 + 3, bB); }
  }

  // ===== phase 2: exact softmax over 512 keys =====
  float mq[4], sq[4], rinv[4];
#pragma unroll
  for (int qt = 0; qt < 4; ++qt) {
    float m = S[0][qt][0];
#pragma unroll
    for (int kt = 0; kt < 2; ++kt)
#pragma unroll
      for (int r = 0; r < 4; ++r) m = fmaxf(m, S[kt][qt][r]);
    m = fmaxf(m, __shfl_xor(m, 16, 64));
    m = fmaxf(m, __shfl_xor(m, 32, 64));
    mq[qt] = m;
  }
  if (h == 0) {
#pragma unroll
    for (int qt = 0; qt < 4; ++qt)
      *(float*)(smem + R6_0 + (wid * 64 + 16 * qt + l15) * 4) = mq[qt];
  }
  __syncthreads();                          // B1
#pragma unroll
  for (int qt = 0; qt < 4; ++qt) {
    float m = -3e38f;
#pragma unroll
    for (int w = 0; w < 16; ++w)
      m = fmaxf(m, *(const float*)(smem + R6_0 + (w * 64 + 16 * qt + l15) * 4));
    mq[qt] = m * SM_SCALE;
    sq[qt] = 0.f;
  }
#pragma unroll
  for (int kt = 0; kt < 2; ++kt)
#pragma unroll
    for (int qt = 0; qt < 4; ++qt)
#pragma unroll
      for (int r = 0; r < 4; ++r) {
        float v = exp2f((S[kt][qt][r] * SM_SCALE - mq[qt]) * LOG2E);
        S[kt][qt][r] = v;
        sq[qt] += v;
      }
#pragma unroll
  for (int qt = 0; qt < 4; ++qt) {
    sq[qt] += __shfl_xor(sq[qt], 16, 64);
    sq[qt] += __shfl_xor(sq[qt], 32, 64);
  }
  if (h == 0) {
#pragma unroll
    for (int qt = 0; qt < 4; ++qt)
      *(float*)(smem + R6_1 + (wid * 64 + 16 * qt + l15) * 4) = sq[qt];
  }
  __syncthreads();                          // B2 (all Q-frag reads done)
#pragma unroll
  for (int qt = 0; qt < 4; ++qt) {
    float l = 0.f;
#pragma unroll
    for (int w = 0; w < 16; ++w)
      l += *(const float*)(smem + R6_1 + (w * 64 + 16 * qt + l15) * 4);
    rinv[qt] = 0.25f / l;                  // fold denom and /r=4 into P
  }
  // P' write, fragment-major: wave wid covers keys [32*wid, +32) == ks group wid.
  // lane' = l15 + 16*(2*kt + (h>>1)); byte = 8*(h&1); values r=0..3 -> bytes +0,2,4,6
#pragma unroll
  for (int kt = 0; kt < 2; ++kt)
#pragma unroll
    for (int qt = 0; qt < 4; ++qt) {
      uint2 w2;
      w2.x = pk2(S[kt][qt][0] * rinv[qt], S[kt][qt][1] * rinv[qt]);
      w2.y = pk2(S[kt][qt][2] * rinv[qt], S[kt][qt][3] * rinv[qt]);
      *(uint2*)(smem + qt * 16384 + wid * 1024 +
                (l15 + 16 * (2 * kt + (h >> 1))) * 16 + 8 * (h & 1)) = w2;
    }
  __syncthreads();                          // B3: P' ready

  // ===== phase 3: O = P V, wave owns 64-d slice, barrier-free =====
  f32x4 acc[4][4];
#pragma unroll
  for (int i = 0; i < 4; ++i)
#pragma unroll
    for (int j = 0; j < 4; ++j) acc[i][j] = (f32x4){0.f, 0.f, 0.f, 0.f};

  const char* vtW = vt + (size_t)prob * 1048576 + (size_t)(64 * wid + l15) * 1024 + 16 * h;

#pragma unroll 2
  for (int ks = 0; ks < 16; ++ks) {
    // pa first (conflict-free canonical lane*16 read), then v (global), then MFMA
    bf16x8 pa[4];
#pragma unroll
    for (int qt = 0; qt < 4; ++qt)
      pa[qt] = *(const bf16x8*)(smem + qt * 16384 + ks * 1024 + lane16);
    bf16x8 v0 = *(const bf16x8*)(vtW + 0 * 16384 + ks * 64);
    bf16x8 v1 = *(const bf16x8*)(vtW + 1 * 16384 + ks * 64);
    bf16x8 v2 = *(const bf16x8*)(vtW + 2 * 16384 + ks * 64);
    bf16x8 v3 = *(const bf16x8*)(vtW + 3 * 16384 + ks * 64);
    __builtin_amdgcn_s_setprio(1);
#pragma unroll
    for (int qt = 0; qt < 4; ++qt) {
      acc[0][qt] = __builtin_amdgcn_mfma_f32_16x16x32_bf16(pa[qt], v0, acc[0][qt], 0, 0, 0);
      acc[1][qt] = __builtin_amdgcn_mfma_f32_16x16x32_bf16(pa[qt], v1, acc[1][qt], 0, 0, 0);
      acc[2][qt] = __builtin_amdgcn_mfma_f32_16x16x32_bf16(pa[qt], v2, acc[2][qt], 0, 0, 0);
      acc[3][qt] = __builtin_amdgcn_mfma_f32_16x16x32_bf16(pa[qt], v3, acc[3][qt], 0, 0, 0);
    }
    __builtin_amdgcn_s_setprio(0);
  }

  // ===== epilogue =====
  float* outW = out + ((size_t)(b * 8192 + gs * 2048 + (q0 + 4 * h) * 4 + off)) * 1024
                + 64 * wid + l15;
#pragma unroll
  for (int cd = 0; cd < 4; ++cd)
#pragma unroll
    for (int qt = 0; qt < 4; ++qt)
#pragma unroll
      for (int r = 0; r < 4; ++r)
        outW[(size_t)((16 * qt + r) * 4) * 1024 + cd * 16] = acc[cd][qt][r];
}

// ======================================================================
// ============ fallback path (round-4, verified PASS) ==================
#define KP_OFF 0
#define Q_OFF  65536
#define RED0   65536
#define RED1   67584
#define LDS_BYTES 73728

__global__ __launch_bounds__(256)
void vt_prepass(const float* __restrict__ x, uint16_t* __restrict__ vt) {
  __shared__ char tl[64 * 144];
  const int t    = threadIdx.x;
  const int blk  = blockIdx.x;
  const int dc   = blk & 15;
  const int kb   = (blk >> 4) & 7;
  const int prob = blk >> 7;
  const int b  = prob >> 4, off = (prob >> 2) & 3, gs = prob & 3;

  const int key = t >> 2, dq = t & 3;
  const float* src = x + ((size_t)(b * 8192 + gs * 2048 + (kb * 64 + key) * 4 + off)) * 1024
                     + dc * 64 + dq * 16;
  float4 f0 = *(const float4*)(src);
  float4 f1 = *(const float4*)(src + 4);
  float4 f2 = *(const float4*)(src + 8);
  float4 f3 = *(const float4*)(src + 12);
  const int swz = (key & 7) << 4;
  *(uint4*)(tl + key * 144 + ((dq * 32) ^ swz))      = pack8(f0, f1);
  *(uint4*)(tl + key * 144 + ((dq * 32 + 16) ^ swz)) = pack8(f2, f3);
  __syncthreads();
  const int d = t >> 2, kq = t & 3;
  uint32_t w[8];
#pragma unroll
  for (int i = 0; i < 8; ++i) {
    int k0 = kq * 16 + 2 * i, k1 = k0 + 1;
    uint32_t a  = *(const uint16_t*)(tl + k0 * 144 + ((2 * d) ^ ((k0 & 7) << 4)));
    uint32_t bb = *(const uint16_t*)(tl + k1 * 144 + ((2 * d) ^ ((k1 & 7) << 4)));
    w[i] = a | (bb << 16);
  }
  uint16_t* dst = vt + ((size_t)(prob * 1024 + dc * 64 + d)) * 512 + kb * 64 + kq * 16;
  *(uint4*)(dst)     = *(uint4*)&w[0];
  *(uint4*)(dst + 8) = *(uint4*)&w[4];
}

template <int USE_VT>
__global__ __launch_bounds__(512, 2)
void dilattn2(const float* __restrict__ x, const uint16_t* __restrict__ vt,
              float* __restrict__ out) {
  extern __shared__ char smem[];

  const int tid  = threadIdx.x;
  const int lane = tid & 63;
  const int wid  = tid >> 6;
  const int h    = lane >> 4;
  const int l15  = lane & 15;
  const int psw  = (l15 & 7) << 4;

  const int blk  = blockIdx.x;
  const int prob = blk >> 3;
  const int q0   = (blk & 7) * 64;
  const int b    = prob >> 4;
  const int off  = (prob >> 2) & 3;
  const int gs   = prob & 3;

  const float* xb = x + (size_t)b * (8192u * 1024u);

  const int srow = tid >> 3;
  const int sg   = tid & 7;
  const float* gK = xb + (size_t)(gs * 2048 + srow * 4 + off) * 1024 + sg * 8;
  const float* gQ = xb + (size_t)(gs * 2048 + (q0 + srow) * 4 + off) * 1024 + sg * 8;
  const int kWr = srow * 128 + ((sg * 16) ^ ((srow & 7) << 4));
  const int qWr = Q_OFF + kWr;

  const int akR = (64 * wid + l15) * 128;
  const int bqR = Q_OFF + l15 * 128;
  const int fb0 = (16 * h) ^ psw;

  f32x4 S[4][4];
#pragma unroll
  for (int i = 0; i < 4; ++i)
#pragma unroll
    for (int j = 0; j < 4; ++j) S[i][j] = (f32x4){0.f, 0.f, 0.f, 0.f};

  float4 kp[16], qp[2];
#pragma unroll
  for (int j = 0; j < 8; ++j) {
    const float* p = gK + (size_t)j * 262144;
    kp[2 * j]     = *(const float4*)(p);
    kp[2 * j + 1] = *(const float4*)(p + 4);
  }
  qp[0] = *(const float4*)(gQ);
  qp[1] = *(const float4*)(gQ + 4);

#pragma unroll 1
  for (int dc = 0; dc < 16; ++dc) {
#pragma unroll
    for (int j = 0; j < 8; ++j)
      *(uint4*)(smem + KP_OFF + kWr + j * 8192) = pack8(kp[2 * j], kp[2 * j + 1]);
    *(uint4*)(smem + qWr) = pack8(qp[0], qp[1]);
    if (dc < 15) {
      const int doff = (dc + 1) * 64;
#pragma unroll
      for (int j = 0; j < 8; ++j) {
        const float* p = gK + (size_t)j * 262144 + doff;
        kp[2 * j]     = *(const float4*)(p);
        kp[2 * j + 1] = *(const float4*)(p + 4);
      }
      qp[0] = *(const float4*)(gQ + doff);
      qp[1] = *(const float4*)(gQ + doff + 4);
    }
    __syncthreads();
#pragma unroll
    for (int s = 0; s < 2; ++s) {
      const int fb = fb0 ^ (s << 6);
      bf16x8 aK[4], bq[4];
#pragma unroll
      for (int kt = 0; kt < 4; ++kt)
        aK[kt] = *(const bf16x8*)(smem + akR + kt * 2048 + fb);
#pragma unroll
      for (int qt = 0; qt < 4; ++qt)
        bq[qt] = *(const bf16x8*)(smem + bqR + qt * 2048 + fb);
#pragma unroll
      for (int kt = 0; kt < 4; ++kt)
#pragma unroll
        for (int qt = 0; qt < 4; ++qt)
          S[kt][qt] = __builtin_amdgcn_mfma_f32_16x16x32_bf16(aK[kt], bq[qt], S[kt][qt], 0, 0, 0);
    }
    __syncthreads();
  }

  float mq[4], sq[4], rinv[4];
#pragma unroll
  for (int qt = 0; qt < 4; ++qt) {
    float m = S[0][qt][0];
#pragma unroll
    for (int kt = 0; kt < 4; ++kt)
#pragma unroll
      for (int r = 0; r < 4; ++r) m = fmaxf(m, S[kt][qt][r]);
    m = fmaxf(m, __shfl_xor(m, 16, 64));
    m = fmaxf(m, __shfl_xor(m, 32, 64));
    mq[qt] = m;
  }
  if (h == 0) {
#pragma unroll
    for (int qt = 0; qt < 4; ++qt)
      *(float*)(smem + RED0 + (wid * 64 + 16 * qt + l15) * 4) = mq[qt];
  }
  __syncthreads();
#pragma unroll
  for (int qt = 0; qt < 4; ++qt) {
    float m = -3e38f;
#pragma unroll
    for (int w = 0; w < 8; ++w)
      m = fmaxf(m, *(const float*)(smem + RED0 + (w * 64 + 16 * qt + l15) * 4));
    mq[qt] = m * SM_SCALE;
    sq[qt] = 0.f;
  }
#pragma unroll
  for (int kt = 0; kt < 4; ++kt)
#pragma unroll
    for (int qt = 0; qt < 4; ++qt)
#pragma unroll
      for (int r = 0; r < 4; ++r) {
        float v = exp2f((S[kt][qt][r] * SM_SCALE - mq[qt]) * LOG2E);
        S[kt][qt][r] = v;
        sq[qt] += v;
      }
#pragma unroll
  for (int qt = 0; qt < 4; ++qt) {
    sq[qt] += __shfl_xor(sq[qt], 16, 64);
    sq[qt] += __shfl_xor(sq[qt], 32, 64);
  }
  if (h == 0) {
#pragma unroll
    for (int qt = 0; qt < 4; ++qt)
      *(float*)(smem + RED1 + (wid * 64 + 16 * qt + l15) * 4) = sq[qt];
  }
  __syncthreads();
#pragma unroll
  for (int qt = 0; qt < 4; ++qt) {
    float l = 0.f;
#pragma unroll
    for (int w = 0; w < 8; ++w)
      l += *(const float*)(smem + RED1 + (w * 64 + 16 * qt + l15) * 4);
    rinv[qt] = 0.25f / l;
  }
#pragma unroll
  for (int kt = 0; kt < 4; ++kt)
#pragma unroll
    for (int qt = 0; qt < 4; ++qt) {
      uint2 w2;
      w2.x = pk2(S[kt][qt][0] * rinv[qt], S[kt][qt][1] * rinv[qt]);
      w2.y = pk2(S[kt][qt][2] * rinv[qt], S[kt][qt][3] * rinv[qt]);
      *(uint2*)(smem + KP_OFF + (16 * qt + l15) * 1024 +
                ((128 * wid + 32 * kt + 8 * h) ^ psw)) = w2;
    }
  __syncthreads();

  f32x4 acc[8][4];
#pragma unroll
  for (int i = 0; i < 8; ++i)
#pragma unroll
    for (int j = 0; j < 4; ++j) acc[i][j] = (f32x4){0.f, 0.f, 0.f, 0.f};

  const uint16_t* vtW = nullptr;
  if constexpr (USE_VT)
    vtW = vt + ((size_t)(prob * 1024 + 128 * wid + l15)) * 512 + 8 * h;

#pragma unroll 1
  for (int ks = 0; ks < 16; ++ks) {
    bf16x8 pa[4];
#pragma unroll
    for (int qt = 0; qt < 4; ++qt)
      pa[qt] = *(const bf16x8*)(smem + KP_OFF + (16 * qt + l15) * 1024 +
                                ((64 * ks + 16 * h) ^ psw));
#pragma unroll
    for (int cd = 0; cd < 8; ++cd) {
      bf16x8 v;
      if constexpr (USE_VT) {
        v = *(const bf16x8*)(vtW + (size_t)((cd >> 2) * 64 + (cd & 3) * 16) * 512 + 32 * ks);
      } else {
        const int d = 128 * wid + (cd >> 2) * 64 + (cd & 3) * 16 + l15;
        union { bf16x8 v; uint16_t u[8]; } a0;
#pragma unroll
        for (int jj = 0; jj < 8; ++jj) {
          int key = 32 * ks + 8 * h + jj;
          a0.u[jj] = (uint16_t)f2bf(xb[(size_t)(gs * 2048 + key * 4 + off) * 1024 + d]);
        }
        v = a0.v;
      }
#pragma unroll
      for (int qt = 0; qt < 4; ++qt)
        acc[cd][qt] = __builtin_amdgcn_mfma_f32_16x16x32_bf16(pa[qt], v, acc[cd][qt], 0, 0, 0);
    }
  }

#pragma unroll
  for (int cd = 0; cd < 8; ++cd) {
    const int d = 128 * wid + (cd >> 2) * 64 + (cd & 3) * 16 + l15;
#pragma unroll
    for (int qt = 0; qt < 4; ++qt)
#pragma unroll
      for (int r = 0; r < 4; ++r) {
        const int qq = q0 + 16 * qt + 4 * h + r;
        out[((size_t)(b * 8192 + gs * 2048 + qq * 4 + off)) * 1024 + d] = acc[cd][qt][r];
      }
  }
}

extern "C" void kernel_launch(void* const* d_in, const int* in_sizes, int n_in,
                              void* d_out, int out_size, void* d_ws, size_t ws_size,
                              hipStream_t stream) {
  const float* x = (const float*)d_in[0];
  float* out = (float*)d_out;
  (void)in_sizes; (void)n_in; (void)out_size;
  const size_t vt_bytes = 64ull * 1024 * 512 * 2;   // 64 MiB
  const size_t xf_bytes = 64ull * 1024 * 1024;      // 64 MiB
  if (ws_size >= vt_bytes + xf_bytes) {
    uint16_t* vtp = (uint16_t*)d_ws;
    uint16_t* xfp = (uint16_t*)((char*)d_ws + vt_bytes);
    hipFuncSetAttribute(reinterpret_cast<const void*>(dilattn6),
                        hipFuncAttributeMaxDynamicSharedMemorySize, LDS6_BYTES);
    prep_comb<<<8192, 256, 0, stream>>>(x, vtp, xfp);
    dilattn6<<<512, 1024, LDS6_BYTES, stream>>>((const char*)xfp, (const char*)vtp, out);
  } else if (ws_size >= vt_bytes) {
    uint16_t* vtp = (uint16_t*)d_ws;
    hipFuncSetAttribute(reinterpret_cast<const void*>(dilattn2<1>),
                        hipFuncAttributeMaxDynamicSharedMemorySize, LDS_BYTES);
    vt_prepass<<<8192, 256, 0, stream>>>(x, vtp);
    dilattn2<1><<<512, 512, LDS_BYTES, stream>>>(x, vtp, out);
  } else {
    hipFuncSetAttribute(reinterpret_cast<const void*>(dilattn2<0>),
                        hipFuncAttributeMaxDynamicSharedMemorySize, LDS_BYTES);
    dilattn2<0><<<512, 512, LDS_BYTES, stream>>>(x, nullptr, out);
  }
}

// Round 10
// 189.808 us; speedup vs baseline: 1.0017x; 1.0017x over previous
//
#include <hip/hip_runtime.h>
#include <stdint.h>

typedef __bf16 bf16x8  __attribute__((ext_vector_type(8)));
typedef float  f32x4   __attribute__((ext_vector_type(4)));

#define LOG2E    1.44269504088896340736f
#define SM_SCALE 0.03125f   /* 1/sqrt(1024) */

typedef __attribute__((address_space(1))) const uint32_t gau32;
typedef __attribute__((address_space(3))) uint32_t       lau32;
#define GLD16(g, l) __builtin_amdgcn_global_load_lds((gau32*)(g), (lau32*)(l), 16, 0, 0)

#define VMW2() asm volatile("s_waitcnt vmcnt(2)" ::: "memory")
#define VMW0() asm volatile("s_waitcnt vmcnt(0)" ::: "memory")
#define VMW4() asm volatile("s_waitcnt vmcnt(4)" ::: "memory")
#define LGKM_BAR() do { asm volatile("s_waitcnt lgkmcnt(0)" ::: "memory"); \
  __builtin_amdgcn_s_barrier(); asm volatile("" ::: "memory"); } while (0)

__device__ __forceinline__ uint32_t f2bf(float f) {
  uint32_t u = __builtin_bit_cast(uint32_t, f);
  u += 0x7FFFu + ((u >> 16) & 1u);   // RNE
  return u >> 16;
}
__device__ __forceinline__ uint32_t pk2(float a, float b) {
  return f2bf(a) | (f2bf(b) << 16);
}
__device__ __forceinline__ uint4 pack8(float4 a, float4 b) {
  uint4 r;
  r.x = pk2(a.x, a.y); r.y = pk2(a.z, a.w);
  r.z = pk2(b.x, b.y); r.w = pk2(b.z, b.w);
  return r;
}

// ================= combined prepass (verified r7-r9; at HBM roofline) =================
__global__ __launch_bounds__(256)
void prep_comb(const float* __restrict__ x, uint16_t* __restrict__ vt,
               uint16_t* __restrict__ xf) {
  __shared__ char tl[64 * 144];
  const int t    = threadIdx.x;
  const int blk  = blockIdx.x;
  const int dc   = blk & 15;          // 64-d chunk
  const int kb   = (blk >> 4) & 7;    // 64-key chunk
  const int prob = blk >> 7;          // 0..63
  const int b  = prob >> 4, off = (prob >> 2) & 3, gs = prob & 3;

  const int key = t >> 2, dq = t & 3;
  const float* src = x + ((size_t)(b * 8192 + gs * 2048 + (kb * 64 + key) * 4 + off)) * 1024
                     + dc * 64 + dq * 16;
  float4 f0 = *(const float4*)(src);
  float4 f1 = *(const float4*)(src + 4);
  float4 f2 = *(const float4*)(src + 8);
  float4 f3 = *(const float4*)(src + 12);
  const int swz = (key & 7) << 4;
  *(uint4*)(tl + key * 144 + ((dq * 32) ^ swz))      = pack8(f0, f1);
  *(uint4*)(tl + key * 144 + ((dq * 32 + 16) ^ swz)) = pack8(f2, f3);
  __syncthreads();
  // vt (transposed)
  {
    const int d = t >> 2, kq = t & 3;
    uint32_t w[8];
#pragma unroll
    for (int i = 0; i < 8; ++i) {
      int k0 = kq * 16 + 2 * i, k1 = k0 + 1;
      uint32_t a  = *(const uint16_t*)(tl + k0 * 144 + ((2 * d) ^ ((k0 & 7) << 4)));
      uint32_t bb = *(const uint16_t*)(tl + k1 * 144 + ((2 * d) ^ ((k1 & 7) << 4)));
      w[i] = a | (bb << 16);
    }
    uint16_t* dst = vt + ((size_t)(prob * 1024 + dc * 64 + d)) * 512 + kb * 64 + kq * 16;
    *(uint4*)(dst)     = *(uint4*)&w[0];
    *(uint4*)(dst + 8) = *(uint4*)&w[4];
  }
  // xf (fragment-major)
  {
    const int row = t >> 2, p = t & 3;
    const int dcl = p >> 1;
    const int dq8b = (p & 1) * 2;
    const int swz2 = (row & 7) << 4;
    char* fbase = (char*)xf +
        (((size_t)(prob * 32 + kb * 4 + (row >> 4)) * 32) + (dc * 2 + dcl)) * 1024;
#pragma unroll
    for (int i = 0; i < 2; ++i) {
      const int dq8 = dq8b + i;
      uint4 w = *(const uint4*)(tl + row * 144 + ((dcl * 64 + dq8 * 16) ^ swz2));
      *(uint4*)(fbase + ((row & 15) + 16 * dq8) * 16) = w;
    }
  }
}

// ================= main kernel v8: GLD16 rings + counted vmcnt =================
// LDS: Q-half [0,65536): [dcl 0..15][qt 0..3][1024B]
//      ring   [65536,131072): per-wave 4 KB = 2 slots x 2 KB (A in ph1, V in ph3)
//      red0 @131072, red1 @135168
//      P' fragment-major [qt][ks][lane][16B] aliases [0,65536) after B2
#define R7_0 131072
#define R7_1 135168
#define LDS7_BYTES 139264

__global__ __launch_bounds__(1024, 4)
void dilattn7(const char* __restrict__ xf, const char* __restrict__ vt,
              float* __restrict__ out) {
  extern __shared__ char smem[];

  const int tid  = threadIdx.x;
  const int lane = tid & 63;
  const int wid  = tid >> 6;          // 0..15
  const int h    = lane >> 4;
  const int l15  = lane & 15;
  const int lane16 = lane * 16;

  const int blk  = blockIdx.x;        // bijective XCD map: prob's 8 q-blocks share XCD
  const int prob = ((blk & 7) << 3) | (blk >> 6);
  const int q0   = ((blk >> 3) & 7) * 64;
  const int b    = prob >> 4;
  const int off  = (prob >> 2) & 3;
  const int gs   = prob & 3;

  const char* xfp = xf + (size_t)prob * 1048576;
  const int qtile0 = q0 >> 4;
  const char* xfA0 = xfp + (size_t)(2 * wid) * 32768 + lane16;
  const char* xfA1 = xfA0 + 32768;
  char* AVw = smem + 65536 + wid * 4096;   // wave-private ring base (GLD16 dest: uniform)

#define STAGE_Q(half) do {                                                           \
    _Pragma("unroll")                                                                \
    for (int i_ = 0; i_ < 4; ++i_) {                                                 \
      const int c_ = wid * 4 + i_;                                                   \
      const int dcl_ = c_ >> 2, qt_ = c_ & 3;                                        \
      GLD16(xfp + ((size_t)(qtile0 + qt_) * 32 + ((half) * 16 + dcl_)) * 1024 + lane16, \
            smem + dcl_ * 4096 + qt_ * 1024); } } while (0)

#define ISSUE_A(ca, s) do {                                                          \
    GLD16(xfA0 + (ca) * 1024, AVw + (s) * 2048);                                     \
    GLD16(xfA1 + (ca) * 1024, AVw + (s) * 2048 + 1024); } while (0)

  f32x4 S[2][4];
#pragma unroll
  for (int i = 0; i < 2; ++i)
#pragma unroll
    for (int j = 0; j < 4; ++j) S[i][j] = (f32x4){0.f, 0.f, 0.f, 0.f};

#define PH1_HALF(base) do {                                                          \
    _Pragma("unroll")                                                                \
    for (int c = 0; c < 16; ++c) {                                                   \
      if (c < 15) { VMW2(); } else { VMW0(); }                                       \
      const char* av_ = AVw + (c & 1) * 2048 + lane16;                               \
      bf16x8 a0 = *(const bf16x8*)(av_);                                             \
      bf16x8 a1 = *(const bf16x8*)(av_ + 1024);                                      \
      const char* qb_ = smem + c * 4096 + lane16;                                    \
      bf16x8 b0 = *(const bf16x8*)(qb_);                                             \
      bf16x8 b1 = *(const bf16x8*)(qb_ + 1024);                                      \
      bf16x8 b2 = *(const bf16x8*)(qb_ + 2048);                                      \
      bf16x8 b3 = *(const bf16x8*)(qb_ + 3072);                                      \
      __builtin_amdgcn_s_setprio(1);                                                 \
      S[0][0] = __builtin_amdgcn_mfma_f32_16x16x32_bf16(a0, b0, S[0][0], 0, 0, 0);   \
      S[0][1] = __builtin_amdgcn_mfma_f32_16x16x32_bf16(a0, b1, S[0][1], 0, 0, 0);   \
      S[0][2] = __builtin_amdgcn_mfma_f32_16x16x32_bf16(a0, b2, S[0][2], 0, 0, 0);   \
      S[0][3] = __builtin_amdgcn_mfma_f32_16x16x32_bf16(a0, b3, S[0][3], 0, 0, 0);   \
      S[1][0] = __builtin_amdgcn_mfma_f32_16x16x32_bf16(a1, b0, S[1][0], 0, 0, 0);   \
      S[1][1] = __builtin_amdgcn_mfma_f32_16x16x32_bf16(a1, b1, S[1][1], 0, 0, 0);   \
      S[1][2] = __builtin_amdgcn_mfma_f32_16x16x32_bf16(a1, b2, S[1][2], 0, 0, 0);   \
      S[1][3] = __builtin_amdgcn_mfma_f32_16x16x32_bf16(a1, b3, S[1][3], 0, 0, 0);   \
      __builtin_amdgcn_s_setprio(0);                                                 \
      if (c < 14) ISSUE_A((base) + c + 2, c & 1);                                    \
    } } while (0)

  // ===== phase 1 =====
  STAGE_Q(0);
  ISSUE_A(0, 0); ISSUE_A(1, 1);
  VMW4();                                   // Q half-0 landed (oldest 4); A may be in flight
  __builtin_amdgcn_s_barrier();
  asm volatile("" ::: "memory");
  PH1_HALF(0);                              // ends drained (vmcnt(0) at c=15)
  LGKM_BAR();                               // all waves done reading Q half-0
  STAGE_Q(1);
  ISSUE_A(16, 0); ISSUE_A(17, 1);
  VMW4();
  __builtin_amdgcn_s_barrier();
  asm volatile("" ::: "memory");
  PH1_HALF(16);

  // ===== phase-3 V prologue: rides through softmax (lgkm-only barriers) =====
  const char* vsrc = vt + (size_t)prob * 1048576 + (size_t)(64 * wid + l15) * 1024 + 16 * h;
#define ISSUE_V(g, s) do {                                                           \
    const int ks_ = (g) >> 1, jp_ = (g) & 1;                                         \
    GLD16(vsrc + (2 * jp_) * 16384 + ks_ * 64, AVw + (s) * 2048);                    \
    GLD16(vsrc + (2 * jp_ + 1) * 16384 + ks_ * 64, AVw + (s) * 2048 + 1024); } while (0)
  ISSUE_V(0, 0); ISSUE_V(1, 1);

  // ===== phase 2: exact softmax over 512 keys =====
  float mq[4], sq[4], rinv[4];
#pragma unroll
  for (int qt = 0; qt < 4; ++qt) {
    float m = S[0][qt][0];
#pragma unroll
    for (int kt = 0; kt < 2; ++kt)
#pragma unroll
      for (int r = 0; r < 4; ++r) m = fmaxf(m, S[kt][qt][r]);
    m = fmaxf(m, __shfl_xor(m, 16, 64));
    m = fmaxf(m, __shfl_xor(m, 32, 64));
    mq[qt] = m;
  }
  if (h == 0) {
#pragma unroll
    for (int qt = 0; qt < 4; ++qt)
      *(float*)(smem + R7_0 + (wid * 64 + 16 * qt + l15) * 4) = mq[qt];
  }
  LGKM_BAR();                               // B1
#pragma unroll
  for (int qt = 0; qt < 4; ++qt) {
    float m = -3e38f;
#pragma unroll
    for (int w = 0; w < 16; ++w)
      m = fmaxf(m, *(const float*)(smem + R7_0 + (w * 64 + 16 * qt + l15) * 4));
    mq[qt] = m * SM_SCALE;
    sq[qt] = 0.f;
  }
#pragma unroll
  for (int kt = 0; kt < 2; ++kt)
#pragma unroll
    for (int qt = 0; qt < 4; ++qt)
#pragma unroll
      for (int r = 0; r < 4; ++r) {
        float v = exp2f((S[kt][qt][r] * SM_SCALE - mq[qt]) * LOG2E);
        S[kt][qt][r] = v;
        sq[qt] += v;
      }
#pragma unroll
  for (int qt = 0; qt < 4; ++qt) {
    sq[qt] += __shfl_xor(sq[qt], 16, 64);
    sq[qt] += __shfl_xor(sq[qt], 32, 64);
  }
  if (h == 0) {
#pragma unroll
    for (int qt = 0; qt < 4; ++qt)
      *(float*)(smem + R7_1 + (wid * 64 + 16 * qt + l15) * 4) = sq[qt];
  }
  LGKM_BAR();                               // B2 (all Q reads long done)
#pragma unroll
  for (int qt = 0; qt < 4; ++qt) {
    float l = 0.f;
#pragma unroll
    for (int w = 0; w < 16; ++w)
      l += *(const float*)(smem + R7_1 + (w * 64 + 16 * qt + l15) * 4);
    rinv[qt] = 0.25f / l;                  // fold denom and /r=4 into P
  }
  // P' write, fragment-major (r9-verified, conflict-free)
#pragma unroll
  for (int kt = 0; kt < 2; ++kt)
#pragma unroll
    for (int qt = 0; qt < 4; ++qt) {
      uint2 w2;
      w2.x = pk2(S[kt][qt][0] * rinv[qt], S[kt][qt][1] * rinv[qt]);
      w2.y = pk2(S[kt][qt][2] * rinv[qt], S[kt][qt][3] * rinv[qt]);
      *(uint2*)(smem + qt * 16384 + wid * 1024 +
                (l15 + 16 * (2 * kt + (h >> 1))) * 16 + 8 * (h & 1)) = w2;
    }
  LGKM_BAR();                               // B3: P' ready (V still in flight)

  // ===== phase 3: O = P V; V via wave-private LDS ring, counted vmcnt =====
  f32x4 acc[4][4];
#pragma unroll
  for (int i = 0; i < 4; ++i)
#pragma unroll
    for (int j = 0; j < 4; ++j) acc[i][j] = (f32x4){0.f, 0.f, 0.f, 0.f};

  bf16x8 pa[4];
#pragma unroll
  for (int g = 0; g < 32; ++g) {
    if (g < 31) { VMW2(); } else { VMW0(); }
    if ((g & 1) == 0) {
      const int ks = g >> 1;
#pragma unroll
      for (int qt = 0; qt < 4; ++qt)
        pa[qt] = *(const bf16x8*)(smem + qt * 16384 + ks * 1024 + lane16);
    }
    const char* av = AVw + (g & 1) * 2048 + lane16;
    bf16x8 va = *(const bf16x8*)(av);
    bf16x8 vb = *(const bf16x8*)(av + 1024);
    const int j0 = (g & 1) * 2;
    __builtin_amdgcn_s_setprio(1);
#pragma unroll
    for (int qt = 0; qt < 4; ++qt) {
      acc[j0][qt]     = __builtin_amdgcn_mfma_f32_16x16x32_bf16(pa[qt], va, acc[j0][qt], 0, 0, 0);
      acc[j0 + 1][qt] = __builtin_amdgcn_mfma_f32_16x16x32_bf16(pa[qt], vb, acc[j0 + 1][qt], 0, 0, 0);
    }
    __builtin_amdgcn_s_setprio(0);
    if (g < 30) ISSUE_V(g + 2, g & 1);
  }

  // ===== epilogue (r9-verified) =====
  float* outW = out + ((size_t)(b * 8192 + gs * 2048 + (q0 + 4 * h) * 4 + off)) * 1024
                + 64 * wid + l15;
#pragma unroll
  for (int cd = 0; cd < 4; ++cd)
#pragma unroll
    for (int qt = 0; qt < 4; ++qt)
#pragma unroll
      for (int r = 0; r < 4; ++r)
        outW[(size_t)((16 * qt + r) * 4) * 1024 + cd * 16] = acc[cd][qt][r];
#undef STAGE_Q
#undef ISSUE_A
#undef ISSUE_V
#undef PH1_HALF
}

// ======================================================================
// ============ fallback path (round-4, verified PASS) ==================
#define KP_OFF 0
#define Q_OFF  65536
#define RED0   65536
#define RED1   67584
#define LDS_BYTES 73728

__global__ __launch_bounds__(256)
void vt_prepass(const float* __restrict__ x, uint16_t* __restrict__ vt) {
  __shared__ char tl[64 * 144];
  const int t    = threadIdx.x;
  const int blk  = blockIdx.x;
  const int dc   = blk & 15;
  const int kb   = (blk >> 4) & 7;
  const int prob = blk >> 7;
  const int b  = prob >> 4, off = (prob >> 2) & 3, gs = prob & 3;

  const int key = t >> 2, dq = t & 3;
  const float* src = x + ((size_t)(b * 8192 + gs * 2048 + (kb * 64 + key) * 4 + off)) * 1024
                     + dc * 64 + dq * 16;
  float4 f0 = *(const float4*)(src);
  float4 f1 = *(const float4*)(src + 4);
  float4 f2 = *(const float4*)(src + 8);
  float4 f3 = *(const float4*)(src + 12);
  const int swz = (key & 7) << 4;
  *(uint4*)(tl + key * 144 + ((dq * 32) ^ swz))      = pack8(f0, f1);
  *(uint4*)(tl + key * 144 + ((dq * 32 + 16) ^ swz)) = pack8(f2, f3);
  __syncthreads();
  const int d = t >> 2, kq = t & 3;
  uint32_t w[8];
#pragma unroll
  for (int i = 0; i < 8; ++i) {
    int k0 = kq * 16 + 2 * i, k1 = k0 + 1;
    uint32_t a  = *(const uint16_t*)(tl + k0 * 144 + ((2 * d) ^ ((k0 & 7) << 4)));
    uint32_t bb = *(const uint16_t*)(tl + k1 * 144 + ((2 * d) ^ ((k1 & 7) << 4)));
    w[i] = a | (bb << 16);
  }
  uint16_t* dst = vt + ((size_t)(prob * 1024 + dc * 64 + d)) * 512 + kb * 64 + kq * 16;
  *(uint4*)(dst)     = *(uint4*)&w[0];
  *(uint4*)(dst + 8) = *(uint4*)&w[4];
}

template <int USE_VT>
__global__ __launch_bounds__(512, 2)
void dilattn2(const float* __restrict__ x, const uint16_t* __restrict__ vt,
              float* __restrict__ out) {
  extern __shared__ char smem[];

  const int tid  = threadIdx.x;
  const int lane = tid & 63;
  const int wid  = tid >> 6;
  const int h    = lane >> 4;
  const int l15  = lane & 15;
  const int psw  = (l15 & 7) << 4;

  const int blk  = blockIdx.x;
  const int prob = blk >> 3;
  const int q0   = (blk & 7) * 64;
  const int b    = prob >> 4;
  const int off  = (prob >> 2) & 3;
  const int gs   = prob & 3;

  const float* xb = x + (size_t)b * (8192u * 1024u);

  const int srow = tid >> 3;
  const int sg   = tid & 7;
  const float* gK = xb + (size_t)(gs * 2048 + srow * 4 + off) * 1024 + sg * 8;
  const float* gQ = xb + (size_t)(gs * 2048 + (q0 + srow) * 4 + off) * 1024 + sg * 8;
  const int kWr = srow * 128 + ((sg * 16) ^ ((srow & 7) << 4));
  const int qWr = Q_OFF + kWr;

  const int akR = (64 * wid + l15) * 128;
  const int bqR = Q_OFF + l15 * 128;
  const int fb0 = (16 * h) ^ psw;

  f32x4 S[4][4];
#pragma unroll
  for (int i = 0; i < 4; ++i)
#pragma unroll
    for (int j = 0; j < 4; ++j) S[i][j] = (f32x4){0.f, 0.f, 0.f, 0.f};

  float4 kp[16], qp[2];
#pragma unroll
  for (int j = 0; j < 8; ++j) {
    const float* p = gK + (size_t)j * 262144;
    kp[2 * j]     = *(const float4*)(p);
    kp[2 * j + 1] = *(const float4*)(p + 4);
  }
  qp[0] = *(const float4*)(gQ);
  qp[1] = *(const float4*)(gQ + 4);

#pragma unroll 1
  for (int dc = 0; dc < 16; ++dc) {
#pragma unroll
    for (int j = 0; j < 8; ++j)
      *(uint4*)(smem + KP_OFF + kWr + j * 8192) = pack8(kp[2 * j], kp[2 * j + 1]);
    *(uint4*)(smem + qWr) = pack8(qp[0], qp[1]);
    if (dc < 15) {
      const int doff = (dc + 1) * 64;
#pragma unroll
      for (int j = 0; j < 8; ++j) {
        const float* p = gK + (size_t)j * 262144 + doff;
        kp[2 * j]     = *(const float4*)(p);
        kp[2 * j + 1] = *(const float4*)(p + 4);
      }
      qp[0] = *(const float4*)(gQ + doff);
      qp[1] = *(const float4*)(gQ + doff + 4);
    }
    __syncthreads();
#pragma unroll
    for (int s = 0; s < 2; ++s) {
      const int fb = fb0 ^ (s << 6);
      bf16x8 aK[4], bq[4];
#pragma unroll
      for (int kt = 0; kt < 4; ++kt)
        aK[kt] = *(const bf16x8*)(smem + akR + kt * 2048 + fb);
#pragma unroll
      for (int qt = 0; qt < 4; ++qt)
        bq[qt] = *(const bf16x8*)(smem + bqR + qt * 2048 + fb);
#pragma unroll
      for (int kt = 0; kt < 4; ++kt)
#pragma unroll
        for (int qt = 0; qt < 4; ++qt)
          S[kt][qt] = __builtin_amdgcn_mfma_f32_16x16x32_bf16(aK[kt], bq[qt], S[kt][qt], 0, 0, 0);
    }
    __syncthreads();
  }

  float mq[4], sq[4], rinv[4];
#pragma unroll
  for (int qt = 0; qt < 4; ++qt) {
    float m = S[0][qt][0];
#pragma unroll
    for (int kt = 0; kt < 4; ++kt)
#pragma unroll
      for (int r = 0; r < 4; ++r) m = fmaxf(m, S[kt][qt][r]);
    m = fmaxf(m, __shfl_xor(m, 16, 64));
    m = fmaxf(m, __shfl_xor(m, 32, 64));
    mq[qt] = m;
  }
  if (h == 0) {
#pragma unroll
    for (int qt = 0; qt < 4; ++qt)
      *(float*)(smem + RED0 + (wid * 64 + 16 * qt + l15) * 4) = mq[qt];
  }
  __syncthreads();
#pragma unroll
  for (int qt = 0; qt < 4; ++qt) {
    float m = -3e38f;
#pragma unroll
    for (int w = 0; w < 8; ++w)
      m = fmaxf(m, *(const float*)(smem + RED0 + (w * 64 + 16 * qt + l15) * 4));
    mq[qt] = m * SM_SCALE;
    sq[qt] = 0.f;
  }
#pragma unroll
  for (int kt = 0; kt < 4; ++kt)
#pragma unroll
    for (int qt = 0; qt < 4; ++qt)
#pragma unroll
      for (int r = 0; r < 4; ++r) {
        float v = exp2f((S[kt][qt][r] * SM_SCALE - mq[qt]) * LOG2E);
        S[kt][qt][r] = v;
        sq[qt] += v;
      }
#pragma unroll
  for (int qt = 0; qt < 4; ++qt) {
    sq[qt] += __shfl_xor(sq[qt], 16, 64);
    sq[qt] += __shfl_xor(sq[qt], 32, 64);
  }
  if (h == 0) {
#pragma unroll
    for (int qt = 0; qt < 4; ++qt)
      *(float*)(smem + RED1 + (wid * 64 + 16 * qt + l15) * 4) = sq[qt];
  }
  __syncthreads();
#pragma unroll
  for (int qt = 0; qt < 4; ++qt) {
    float l = 0.f;
#pragma unroll
    for (int w = 0; w < 8; ++w)
      l += *(const float*)(smem + RED1 + (w * 64 + 16 * qt + l15) * 4);
    rinv[qt] = 0.25f / l;
  }
#pragma unroll
  for (int kt = 0; kt < 4; ++kt)
#pragma unroll
    for (int qt = 0; qt < 4; ++qt) {
      uint2 w2;
      w2.x = pk2(S[kt][qt][0] * rinv[qt], S[kt][qt][1] * rinv[qt]);
      w2.y = pk2(S[kt][qt][2] * rinv[qt], S[kt][qt][3] * rinv[qt]);
      *(uint2*)(smem + KP_OFF + (16 * qt + l15) * 1024 +
                ((128 * wid + 32 * kt + 8 * h) ^ psw)) = w2;
    }
  __syncthreads();

  f32x4 acc[8][4];
#pragma unroll
  for (int i = 0; i < 8; ++i)
#pragma unroll
    for (int j = 0; j < 4; ++j) acc[i][j] = (f32x4){0.f, 0.f, 0.f, 0.f};

  const uint16_t* vtW = nullptr;
  if constexpr (USE_VT)
    vtW = vt + ((size_t)(prob * 1024 + 128 * wid + l15)) * 512 + 8 * h;

#pragma unroll 1
  for (int ks = 0; ks < 16; ++ks) {
    bf16x8 pa[4];
#pragma unroll
    for (int qt = 0; qt < 4; ++qt)
      pa[qt] = *(const bf16x8*)(smem + KP_OFF + (16 * qt + l15) * 1024 +
                                ((64 * ks + 16 * h) ^ psw));
#pragma unroll
    for (int cd = 0; cd < 8; ++cd) {
      bf16x8 v;
      if constexpr (USE_VT) {
        v = *(const bf16x8*)(vtW + (size_t)((cd >> 2) * 64 + (cd & 3) * 16) * 512 + 32 * ks);
      } else {
        const int d = 128 * wid + (cd >> 2) * 64 + (cd & 3) * 16 + l15;
        union { bf16x8 v; uint16_t u[8]; } a0;
#pragma unroll
        for (int jj = 0; jj < 8; ++jj) {
          int key = 32 * ks + 8 * h + jj;
          a0.u[jj] = (uint16_t)f2bf(xb[(size_t)(gs * 2048 + key * 4 + off) * 1024 + d]);
        }
        v = a0.v;
      }
#pragma unroll
      for (int qt = 0; qt < 4; ++qt)
        acc[cd][qt] = __builtin_amdgcn_mfma_f32_16x16x32_bf16(pa[qt], v, acc[cd][qt], 0, 0, 0);
    }
  }

#pragma unroll
  for (int cd = 0; cd < 8; ++cd) {
    const int d = 128 * wid + (cd >> 2) * 64 + (cd & 3) * 16 + l15;
#pragma unroll
    for (int qt = 0; qt < 4; ++qt)
#pragma unroll
      for (int r = 0; r < 4; ++r) {
        const int qq = q0 + 16 * qt + 4 * h + r;
        out[((size_t)(b * 8192 + gs * 2048 + qq * 4 + off)) * 1024 + d] = acc[cd][qt][r];
      }
  }
}

extern "C" void kernel_launch(void* const* d_in, const int* in_sizes, int n_in,
                              void* d_out, int out_size, void* d_ws, size_t ws_size,
                              hipStream_t stream) {
  const float* x = (const float*)d_in[0];
  float* out = (float*)d_out;
  (void)in_sizes; (void)n_in; (void)out_size;
  const size_t vt_bytes = 64ull * 1024 * 512 * 2;   // 64 MiB
  const size_t xf_bytes = 64ull * 1024 * 1024;      // 64 MiB
  if (ws_size >= vt_bytes + xf_bytes) {
    uint16_t* vtp = (uint16_t*)d_ws;
    uint16_t* xfp = (uint16_t*)((char*)d_ws + vt_bytes);
    hipFuncSetAttribute(reinterpret_cast<const void*>(dilattn7),
                        hipFuncAttributeMaxDynamicSharedMemorySize, LDS7_BYTES);
    prep_comb<<<8192, 256, 0, stream>>>(x, vtp, xfp);
    dilattn7<<<512, 1024, LDS7_BYTES, stream>>>((const char*)xfp, (const char*)vtp, out);
  } else if (ws_size >= vt_bytes) {
    uint16_t* vtp = (uint16_t*)d_ws;
    hipFuncSetAttribute(reinterpret_cast<const void*>(dilattn2<1>),
                        hipFuncAttributeMaxDynamicSharedMemorySize, LDS_BYTES);
    vt_prepass<<<8192, 256, 0, stream>>>(x, vtp);
    dilattn2<1><<<512, 512, LDS_BYTES, stream>>>(x, vtp, out);
  } else {
    hipFuncSetAttribute(reinterpret_cast<const void*>(dilattn2<0>),
                        hipFuncAttributeMaxDynamicSharedMemorySize, LDS_BYTES);
    dilattn2<0><<<512, 512, LDS_BYTES, stream>>>(x, nullptr, out);
  }
}

// Round 11
// 189.101 us; speedup vs baseline: 1.0055x; 1.0037x over previous
//
#include <hip/hip_runtime.h>
#include <stdint.h>

typedef __bf16 bf16x8  __attribute__((ext_vector_type(8)));
typedef float  f32x4   __attribute__((ext_vector_type(4)));

#define LOG2E    1.44269504088896340736f
#define SM_SCALE 0.03125f   /* 1/sqrt(1024) */

typedef __attribute__((address_space(1))) const uint32_t gau32;
typedef __attribute__((address_space(3))) uint32_t       lau32;
#define GLD16(g, l) __builtin_amdgcn_global_load_lds((gau32*)(g), (lau32*)(l), 16, 0, 0)

__device__ __forceinline__ uint32_t f2bf(float f) {
  uint32_t u = __builtin_bit_cast(uint32_t, f);
  u += 0x7FFFu + ((u >> 16) & 1u);   // RNE
  return u >> 16;
}
__device__ __forceinline__ uint32_t pk2(float a, float b) {
  return f2bf(a) | (f2bf(b) << 16);
}
__device__ __forceinline__ uint4 pack8(float4 a, float4 b) {
  uint4 r;
  r.x = pk2(a.x, a.y); r.y = pk2(a.z, a.w);
  r.z = pk2(b.x, b.y); r.w = pk2(b.z, b.w);
  return r;
}

// ================= combined prepass (verified r7-r10; at HBM roofline) =================
__global__ __launch_bounds__(256)
void prep_comb(const float* __restrict__ x, uint16_t* __restrict__ vt,
               uint16_t* __restrict__ xf) {
  __shared__ char tl[64 * 144];
  const int t    = threadIdx.x;
  const int blk  = blockIdx.x;
  const int dc   = blk & 15;          // 64-d chunk
  const int kb   = (blk >> 4) & 7;    // 64-key chunk
  const int prob = blk >> 7;          // 0..63
  const int b  = prob >> 4, off = (prob >> 2) & 3, gs = prob & 3;

  const int key = t >> 2, dq = t & 3;
  const float* src = x + ((size_t)(b * 8192 + gs * 2048 + (kb * 64 + key) * 4 + off)) * 1024
                     + dc * 64 + dq * 16;
  float4 f0 = *(const float4*)(src);
  float4 f1 = *(const float4*)(src + 4);
  float4 f2 = *(const float4*)(src + 8);
  float4 f3 = *(const float4*)(src + 12);
  const int swz = (key & 7) << 4;
  *(uint4*)(tl + key * 144 + ((dq * 32) ^ swz))      = pack8(f0, f1);
  *(uint4*)(tl + key * 144 + ((dq * 32 + 16) ^ swz)) = pack8(f2, f3);
  __syncthreads();
  // vt (transposed)
  {
    const int d = t >> 2, kq = t & 3;
    uint32_t w[8];
#pragma unroll
    for (int i = 0; i < 8; ++i) {
      int k0 = kq * 16 + 2 * i, k1 = k0 + 1;
      uint32_t a  = *(const uint16_t*)(tl + k0 * 144 + ((2 * d) ^ ((k0 & 7) << 4)));
      uint32_t bb = *(const uint16_t*)(tl + k1 * 144 + ((2 * d) ^ ((k1 & 7) << 4)));
      w[i] = a | (bb << 16);
    }
    uint16_t* dst = vt + ((size_t)(prob * 1024 + dc * 64 + d)) * 512 + kb * 64 + kq * 16;
    *(uint4*)(dst)     = *(uint4*)&w[0];
    *(uint4*)(dst + 8) = *(uint4*)&w[4];
  }
  // xf (fragment-major)
  {
    const int row = t >> 2, p = t & 3;
    const int dcl = p >> 1;
    const int dq8b = (p & 1) * 2;
    const int swz2 = (row & 7) << 4;
    char* fbase = (char*)xf +
        (((size_t)(prob * 32 + kb * 4 + (row >> 4)) * 32) + (dc * 2 + dcl)) * 1024;
#pragma unroll
    for (int i = 0; i < 2; ++i) {
      const int dq8 = dq8b + i;
      uint4 w = *(const uint4*)(tl + row * 144 + ((dcl * 64 + dq8 * 16) ^ swz2));
      *(uint4*)(fbase + ((row & 15) + 16 * dq8) * 16) = w;
    }
  }
}

// ============ main kernel v9: r8 structure, spill-free -> TRUE 2 blocks/CU ============
// LDS: Q-half [0,65536): [dcl 0..15][qt 0..3][1024B]; red0 @65536; red1 @67584
// P [64 q][1024 B] aliases [0,65536). Total 68 KB -> two blocks co-resident.
#define R8_0 65536
#define R8_1 67584
#define LDS8_BYTES 69632

__global__ __launch_bounds__(512, 4)   // hard 128-reg cap; live state trimmed to ~112
void dilattn8(const char* __restrict__ xf, const char* __restrict__ vt,
              float* __restrict__ out) {
  extern __shared__ char smem[];

  const int tid  = threadIdx.x;
  const int lane = tid & 63;
  const int wid  = tid >> 6;          // 0..7
  const int h    = lane >> 4;
  const int l15  = lane & 15;
  const int psw  = (l15 & 7) << 4;
  const int lane16 = lane * 16;

  const int blk  = blockIdx.x;        // bijective XCD map: a prob's 8 q-blocks share XCD
  const int prob = ((blk & 7) << 3) | (blk >> 6);
  const int q0   = ((blk >> 3) & 7) * 64;
  const int b    = prob >> 4;
  const int off  = (prob >> 2) & 3;
  const int gs   = prob & 3;

  const char* xfp = xf + (size_t)prob * 1048576;
  const int qtile0 = q0 >> 4;
  const char* xfA = xfp + (size_t)(4 * wid) * 32768 + lane16;   // wave's 4 ktiles

#define STAGE_HALF8(half) do {                                                   \
    _Pragma("unroll")                                                            \
    for (int i_ = 0; i_ < 8; ++i_) {                                             \
      const int c_ = wid * 8 + i_;                                               \
      const int dcl_ = c_ >> 2, qt_ = c_ & 3;                                    \
      GLD16(xfp + ((size_t)(qtile0 + qt_) * 32 + ((half) * 16 + dcl_)) * 1024 + lane16, \
            smem + dcl_ * 4096 + qt_ * 1024); } } while (0)

  f32x4 S[4][4];
#pragma unroll
  for (int i = 0; i < 4; ++i)
#pragma unroll
    for (int j = 0; j < 4; ++j) S[i][j] = (f32x4){0.f, 0.f, 0.f, 0.f};

  // ===== phase 1: S = K Q^T; Q staged in two 512-d halves; A depth-1 from global =====
#pragma unroll 1
  for (int half = 0; half < 2; ++half) {
    STAGE_HALF8(half);
    __syncthreads();                       // half staged (drains GLD16s)
#pragma unroll
    for (int dc = 0; dc < 16; ++dc) {
      const int dca = half * 16 + dc;
      const char* qb = smem + dc * 4096 + lane16;
      bf16x8 b0 = *(const bf16x8*)(qb);
      bf16x8 b1 = *(const bf16x8*)(qb + 1024);
      bf16x8 b2 = *(const bf16x8*)(qb + 2048);
      bf16x8 b3 = *(const bf16x8*)(qb + 3072);
#pragma unroll
      for (int ktp = 0; ktp < 2; ++ktp) {
        bf16x8 a0 = *(const bf16x8*)(xfA + (2 * ktp + 0) * 32768 + dca * 1024);
        bf16x8 a1 = *(const bf16x8*)(xfA + (2 * ktp + 1) * 32768 + dca * 1024);
        const int k0 = 2 * ktp, k1 = 2 * ktp + 1;
        S[k0][0] = __builtin_amdgcn_mfma_f32_16x16x32_bf16(a0, b0, S[k0][0], 0, 0, 0);
        S[k0][1] = __builtin_amdgcn_mfma_f32_16x16x32_bf16(a0, b1, S[k0][1], 0, 0, 0);
        S[k0][2] = __builtin_amdgcn_mfma_f32_16x16x32_bf16(a0, b2, S[k0][2], 0, 0, 0);
        S[k0][3] = __builtin_amdgcn_mfma_f32_16x16x32_bf16(a0, b3, S[k0][3], 0, 0, 0);
        S[k1][0] = __builtin_amdgcn_mfma_f32_16x16x32_bf16(a1, b0, S[k1][0], 0, 0, 0);
        S[k1][1] = __builtin_amdgcn_mfma_f32_16x16x32_bf16(a1, b1, S[k1][1], 0, 0, 0);
        S[k1][2] = __builtin_amdgcn_mfma_f32_16x16x32_bf16(a1, b2, S[k1][2], 0, 0, 0);
        S[k1][3] = __builtin_amdgcn_mfma_f32_16x16x32_bf16(a1, b3, S[k1][3], 0, 0, 0);
      }
    }
    __syncthreads();                       // all waves done reading this half
  }

  // ===== phase 2: exact softmax over 512 keys (r8-verified formulas) =====
  float mq[4], sq[4], rinv[4];
#pragma unroll
  for (int qt = 0; qt < 4; ++qt) {
    float m = S[0][qt][0];
#pragma unroll
    for (int kt = 0; kt < 4; ++kt)
#pragma unroll
      for (int r = 0; r < 4; ++r) m = fmaxf(m, S[kt][qt][r]);
    m = fmaxf(m, __shfl_xor(m, 16, 64));
    m = fmaxf(m, __shfl_xor(m, 32, 64));
    mq[qt] = m;
  }
  if (h == 0) {
#pragma unroll
    for (int qt = 0; qt < 4; ++qt)
      *(float*)(smem + R8_0 + (wid * 64 + 16 * qt + l15) * 4) = mq[qt];
  }
  __syncthreads();                          // B1
#pragma unroll
  for (int qt = 0; qt < 4; ++qt) {
    float m = -3e38f;
#pragma unroll
    for (int w = 0; w < 8; ++w)
      m = fmaxf(m, *(const float*)(smem + R8_0 + (w * 64 + 16 * qt + l15) * 4));
    mq[qt] = m * SM_SCALE;
    sq[qt] = 0.f;
  }
#pragma unroll
  for (int kt = 0; kt < 4; ++kt)
#pragma unroll
    for (int qt = 0; qt < 4; ++qt)
#pragma unroll
      for (int r = 0; r < 4; ++r) {
        float v = exp2f((S[kt][qt][r] * SM_SCALE - mq[qt]) * LOG2E);
        S[kt][qt][r] = v;
        sq[qt] += v;
      }
#pragma unroll
  for (int qt = 0; qt < 4; ++qt) {
    sq[qt] += __shfl_xor(sq[qt], 16, 64);
    sq[qt] += __shfl_xor(sq[qt], 32, 64);
  }
  if (h == 0) {
#pragma unroll
    for (int qt = 0; qt < 4; ++qt)
      *(float*)(smem + R8_1 + (wid * 64 + 16 * qt + l15) * 4) = sq[qt];
  }
  __syncthreads();                          // B2 (all Q-frag reads done)
#pragma unroll
  for (int qt = 0; qt < 4; ++qt) {
    float l = 0.f;
#pragma unroll
    for (int w = 0; w < 8; ++w)
      l += *(const float*)(smem + R8_1 + (w * 64 + 16 * qt + l15) * 4);
    rinv[qt] = 0.25f / l;                  // fold denom and /r=4 into P
  }
  // P write (r8-verified): row q=16qt+l15, key byte = (128*wid + 32*kt + 8*h) ^ psw
#pragma unroll
  for (int kt = 0; kt < 4; ++kt)
#pragma unroll
    for (int qt = 0; qt < 4; ++qt) {
      uint2 w2;
      w2.x = pk2(S[kt][qt][0] * rinv[qt], S[kt][qt][1] * rinv[qt]);
      w2.y = pk2(S[kt][qt][2] * rinv[qt], S[kt][qt][3] * rinv[qt]);
      *(uint2*)(smem + (16 * qt + l15) * 1024 +
                ((128 * wid + 32 * kt + 8 * h) ^ psw)) = w2;
    }
  __syncthreads();                          // B3: P ready

  // ===== phase 3: O = P V, two 64-d passes per wave, V in pairs (r8-verified) =====
  const char* paB = smem + l15 * 1024;
#pragma unroll 1
  for (int p = 0; p < 2; ++p) {
    const int dbase = 128 * wid + 64 * p;
    f32x4 acc[4][4];
#pragma unroll
    for (int i = 0; i < 4; ++i)
#pragma unroll
      for (int j = 0; j < 4; ++j) acc[i][j] = (f32x4){0.f, 0.f, 0.f, 0.f};

    const char* vtW = vt + (size_t)prob * 1048576 + (size_t)(dbase + l15) * 1024 + 16 * h;
#pragma unroll 2
    for (int ks = 0; ks < 16; ++ks) {
      bf16x8 pa[4];
#pragma unroll
      for (int qt = 0; qt < 4; ++qt)
        pa[qt] = *(const bf16x8*)(paB + qt * 16384 + ((64 * ks + 16 * h) ^ psw));
      {
        bf16x8 v0 = *(const bf16x8*)(vtW + 0 * 16384 + ks * 64);
        bf16x8 v1 = *(const bf16x8*)(vtW + 1 * 16384 + ks * 64);
#pragma unroll
        for (int qt = 0; qt < 4; ++qt) {
          acc[0][qt] = __builtin_amdgcn_mfma_f32_16x16x32_bf16(pa[qt], v0, acc[0][qt], 0, 0, 0);
          acc[1][qt] = __builtin_amdgcn_mfma_f32_16x16x32_bf16(pa[qt], v1, acc[1][qt], 0, 0, 0);
        }
      }
      {
        bf16x8 v2 = *(const bf16x8*)(vtW + 2 * 16384 + ks * 64);
        bf16x8 v3 = *(const bf16x8*)(vtW + 3 * 16384 + ks * 64);
#pragma unroll
        for (int qt = 0; qt < 4; ++qt) {
          acc[2][qt] = __builtin_amdgcn_mfma_f32_16x16x32_bf16(pa[qt], v2, acc[2][qt], 0, 0, 0);
          acc[3][qt] = __builtin_amdgcn_mfma_f32_16x16x32_bf16(pa[qt], v3, acc[3][qt], 0, 0, 0);
        }
      }
    }
    float* outW = out + ((size_t)(b * 8192 + gs * 2048 + (q0 + 4 * h) * 4 + off)) * 1024
                  + dbase + l15;
#pragma unroll
    for (int cd = 0; cd < 4; ++cd)
#pragma unroll
      for (int qt = 0; qt < 4; ++qt)
#pragma unroll
        for (int r = 0; r < 4; ++r)
          outW[(size_t)((16 * qt + r) * 4) * 1024 + cd * 16] = acc[cd][qt][r];
  }
#undef STAGE_HALF8
}

// ======================================================================
// ============ fallback path (round-4, verified PASS) ==================
#define KP_OFF 0
#define Q_OFF  65536
#define RED0   65536
#define RED1   67584
#define LDS_BYTES 73728

__global__ __launch_bounds__(256)
void vt_prepass(const float* __restrict__ x, uint16_t* __restrict__ vt) {
  __shared__ char tl[64 * 144];
  const int t    = threadIdx.x;
  const int blk  = blockIdx.x;
  const int dc   = blk & 15;
  const int kb   = (blk >> 4) & 7;
  const int prob = blk >> 7;
  const int b  = prob >> 4, off = (prob >> 2) & 3, gs = prob & 3;

  const int key = t >> 2, dq = t & 3;
  const float* src = x + ((size_t)(b * 8192 + gs * 2048 + (kb * 64 + key) * 4 + off)) * 1024
                     + dc * 64 + dq * 16;
  float4 f0 = *(const float4*)(src);
  float4 f1 = *(const float4*)(src + 4);
  float4 f2 = *(const float4*)(src + 8);
  float4 f3 = *(const float4*)(src + 12);
  const int swz = (key & 7) << 4;
  *(uint4*)(tl + key * 144 + ((dq * 32) ^ swz))      = pack8(f0, f1);
  *(uint4*)(tl + key * 144 + ((dq * 32 + 16) ^ swz)) = pack8(f2, f3);
  __syncthreads();
  const int d = t >> 2, kq = t & 3;
  uint32_t w[8];
#pragma unroll
  for (int i = 0; i < 8; ++i) {
    int k0 = kq * 16 + 2 * i, k1 = k0 + 1;
    uint32_t a  = *(const uint16_t*)(tl + k0 * 144 + ((2 * d) ^ ((k0 & 7) << 4)));
    uint32_t bb = *(const uint16_t*)(tl + k1 * 144 + ((2 * d) ^ ((k1 & 7) << 4)));
    w[i] = a | (bb << 16);
  }
  uint16_t* dst = vt + ((size_t)(prob * 1024 + dc * 64 + d)) * 512 + kb * 64 + kq * 16;
  *(uint4*)(dst)     = *(uint4*)&w[0];
  *(uint4*)(dst + 8) = *(uint4*)&w[4];
}

template <int USE_VT>
__global__ __launch_bounds__(512, 2)
void dilattn2(const float* __restrict__ x, const uint16_t* __restrict__ vt,
              float* __restrict__ out) {
  extern __shared__ char smem[];

  const int tid  = threadIdx.x;
  const int lane = tid & 63;
  const int wid  = tid >> 6;
  const int h    = lane >> 4;
  const int l15  = lane & 15;
  const int psw  = (l15 & 7) << 4;

  const int blk  = blockIdx.x;
  const int prob = blk >> 3;
  const int q0   = (blk & 7) * 64;
  const int b    = prob >> 4;
  const int off  = (prob >> 2) & 3;
  const int gs   = prob & 3;

  const float* xb = x + (size_t)b * (8192u * 1024u);

  const int srow = tid >> 3;
  const int sg   = tid & 7;
  const float* gK = xb + (size_t)(gs * 2048 + srow * 4 + off) * 1024 + sg * 8;
  const float* gQ = xb + (size_t)(gs * 2048 + (q0 + srow) * 4 + off) * 1024 + sg * 8;
  const int kWr = srow * 128 + ((sg * 16) ^ ((srow & 7) << 4));
  const int qWr = Q_OFF + kWr;

  const int akR = (64 * wid + l15) * 128;
  const int bqR = Q_OFF + l15 * 128;
  const int fb0 = (16 * h) ^ psw;

  f32x4 S[4][4];
#pragma unroll
  for (int i = 0; i < 4; ++i)
#pragma unroll
    for (int j = 0; j < 4; ++j) S[i][j] = (f32x4){0.f, 0.f, 0.f, 0.f};

  float4 kp[16], qp[2];
#pragma unroll
  for (int j = 0; j < 8; ++j) {
    const float* p = gK + (size_t)j * 262144;
    kp[2 * j]     = *(const float4*)(p);
    kp[2 * j + 1] = *(const float4*)(p + 4);
  }
  qp[0] = *(const float4*)(gQ);
  qp[1] = *(const float4*)(gQ + 4);

#pragma unroll 1
  for (int dc = 0; dc < 16; ++dc) {
#pragma unroll
    for (int j = 0; j < 8; ++j)
      *(uint4*)(smem + KP_OFF + kWr + j * 8192) = pack8(kp[2 * j], kp[2 * j + 1]);
    *(uint4*)(smem + qWr) = pack8(qp[0], qp[1]);
    if (dc < 15) {
      const int doff = (dc + 1) * 64;
#pragma unroll
      for (int j = 0; j < 8; ++j) {
        const float* p = gK + (size_t)j * 262144 + doff;
        kp[2 * j]     = *(const float4*)(p);
        kp[2 * j + 1] = *(const float4*)(p + 4);
      }
      qp[0] = *(const float4*)(gQ + doff);
      qp[1] = *(const float4*)(gQ + doff + 4);
    }
    __syncthreads();
#pragma unroll
    for (int s = 0; s < 2; ++s) {
      const int fb = fb0 ^ (s << 6);
      bf16x8 aK[4], bq[4];
#pragma unroll
      for (int kt = 0; kt < 4; ++kt)
        aK[kt] = *(const bf16x8*)(smem + akR + kt * 2048 + fb);
#pragma unroll
      for (int qt = 0; qt < 4; ++qt)
        bq[qt] = *(const bf16x8*)(smem + bqR + qt * 2048 + fb);
#pragma unroll
      for (int kt = 0; kt < 4; ++kt)
#pragma unroll
        for (int qt = 0; qt < 4; ++qt)
          S[kt][qt] = __builtin_amdgcn_mfma_f32_16x16x32_bf16(aK[kt], bq[qt], S[kt][qt], 0, 0, 0);
    }
    __syncthreads();
  }

  float mq[4], sq[4], rinv[4];
#pragma unroll
  for (int qt = 0; qt < 4; ++qt) {
    float m = S[0][qt][0];
#pragma unroll
    for (int kt = 0; kt < 4; ++kt)
#pragma unroll
      for (int r = 0; r < 4; ++r) m = fmaxf(m, S[kt][qt][r]);
    m = fmaxf(m, __shfl_xor(m, 16, 64));
    m = fmaxf(m, __shfl_xor(m, 32, 64));
    mq[qt] = m;
  }
  if (h == 0) {
#pragma unroll
    for (int qt = 0; qt < 4; ++qt)
      *(float*)(smem + RED0 + (wid * 64 + 16 * qt + l15) * 4) = mq[qt];
  }
  __syncthreads();
#pragma unroll
  for (int qt = 0; qt < 4; ++qt) {
    float m = -3e38f;
#pragma unroll
    for (int w = 0; w < 8; ++w)
      m = fmaxf(m, *(const float*)(smem + RED0 + (w * 64 + 16 * qt + l15) * 4));
    mq[qt] = m * SM_SCALE;
    sq[qt] = 0.f;
  }
#pragma unroll
  for (int kt = 0; kt < 4; ++kt)
#pragma unroll
    for (int qt = 0; qt < 4; ++qt)
#pragma unroll
      for (int r = 0; r < 4; ++r) {
        float v = exp2f((S[kt][qt][r] * SM_SCALE - mq[qt]) * LOG2E);
        S[kt][qt][r] = v;
        sq[qt] += v;
      }
#pragma unroll
  for (int qt = 0; qt < 4; ++qt) {
    sq[qt] += __shfl_xor(sq[qt], 16, 64);
    sq[qt] += __shfl_xor(sq[qt], 32, 64);
  }
  if (h == 0) {
#pragma unroll
    for (int qt = 0; qt < 4; ++qt)
      *(float*)(smem + RED1 + (wid * 64 + 16 * qt + l15) * 4) = sq[qt];
  }
  __syncthreads();
#pragma unroll
  for (int qt = 0; qt < 4; ++qt) {
    float l = 0.f;
#pragma unroll
    for (int w = 0; w < 8; ++w)
      l += *(const float*)(smem + RED1 + (w * 64 + 16 * qt + l15) * 4);
    rinv[qt] = 0.25f / l;
  }
#pragma unroll
  for (int kt = 0; kt < 4; ++kt)
#pragma unroll
    for (int qt = 0; qt < 4; ++qt) {
      uint2 w2;
      w2.x = pk2(S[kt][qt][0] * rinv[qt], S[kt][qt][1] * rinv[qt]);
      w2.y = pk2(S[kt][qt][2] * rinv[qt], S[kt][qt][3] * rinv[qt]);
      *(uint2*)(smem + KP_OFF + (16 * qt + l15) * 1024 +
                ((128 * wid + 32 * kt + 8 * h) ^ psw)) = w2;
    }
  __syncthreads();

  f32x4 acc[8][4];
#pragma unroll
  for (int i = 0; i < 8; ++i)
#pragma unroll
    for (int j = 0; j < 4; ++j) acc[i][j] = (f32x4){0.f, 0.f, 0.f, 0.f};

  const uint16_t* vtW = nullptr;
  if constexpr (USE_VT)
    vtW = vt + ((size_t)(prob * 1024 + 128 * wid + l15)) * 512 + 8 * h;

#pragma unroll 1
  for (int ks = 0; ks < 16; ++ks) {
    bf16x8 pa[4];
#pragma unroll
    for (int qt = 0; qt < 4; ++qt)
      pa[qt] = *(const bf16x8*)(smem + KP_OFF + (16 * qt + l15) * 1024 +
                                ((64 * ks + 16 * h) ^ psw));
#pragma unroll
    for (int cd = 0; cd < 8; ++cd) {
      bf16x8 v;
      if constexpr (USE_VT) {
        v = *(const bf16x8*)(vtW + (size_t)((cd >> 2) * 64 + (cd & 3) * 16) * 512 + 32 * ks);
      } else {
        const int d = 128 * wid + (cd >> 2) * 64 + (cd & 3) * 16 + l15;
        union { bf16x8 v; uint16_t u[8]; } a0;
#pragma unroll
        for (int jj = 0; jj < 8; ++jj) {
          int key = 32 * ks + 8 * h + jj;
          a0.u[jj] = (uint16_t)f2bf(xb[(size_t)(gs * 2048 + key * 4 + off) * 1024 + d]);
        }
        v = a0.v;
      }
#pragma unroll
      for (int qt = 0; qt < 4; ++qt)
        acc[cd][qt] = __builtin_amdgcn_mfma_f32_16x16x32_bf16(pa[qt], v, acc[cd][qt], 0, 0, 0);
    }
  }

#pragma unroll
  for (int cd = 0; cd < 8; ++cd) {
    const int d = 128 * wid + (cd >> 2) * 64 + (cd & 3) * 16 + l15;
#pragma unroll
    for (int qt = 0; qt < 4; ++qt)
#pragma unroll
      for (int r = 0; r < 4; ++r) {
        const int qq = q0 + 16 * qt + 4 * h + r;
        out[((size_t)(b * 8192 + gs * 2048 + qq * 4 + off)) * 1024 + d] = acc[cd][qt][r];
      }
  }
}

extern "C" void kernel_launch(void* const* d_in, const int* in_sizes, int n_in,
                              void* d_out, int out_size, void* d_ws, size_t ws_size,
                              hipStream_t stream) {
  const float* x = (const float*)d_in[0];
  float* out = (float*)d_out;
  (void)in_sizes; (void)n_in; (void)out_size;
  const size_t vt_bytes = 64ull * 1024 * 512 * 2;   // 64 MiB
  const size_t xf_bytes = 64ull * 1024 * 1024;      // 64 MiB
  if (ws_size >= vt_bytes + xf_bytes) {
    uint16_t* vtp = (uint16_t*)d_ws;
    uint16_t* xfp = (uint16_t*)((char*)d_ws + vt_bytes);
    hipFuncSetAttribute(reinterpret_cast<const void*>(dilattn8),
                        hipFuncAttributeMaxDynamicSharedMemorySize, LDS8_BYTES);
    prep_comb<<<8192, 256, 0, stream>>>(x, vtp, xfp);
    dilattn8<<<512, 512, LDS8_BYTES, stream>>>((const char*)xfp, (const char*)vtp, out);
  } else if (ws_size >= vt_bytes) {
    uint16_t* vtp = (uint16_t*)d_ws;
    hipFuncSetAttribute(reinterpret_cast<const void*>(dilattn2<1>),
                        hipFuncAttributeMaxDynamicSharedMemorySize, LDS_BYTES);
    vt_prepass<<<8192, 256, 0, stream>>>(x, vtp);
    dilattn2<1><<<512, 512, LDS_BYTES, stream>>>(x, vtp, out);
  } else {
    hipFuncSetAttribute(reinterpret_cast<const void*>(dilattn2<0>),
                        hipFuncAttributeMaxDynamicSharedMemorySize, LDS_BYTES);
    dilattn2<0><<<512, 512, LDS_BYTES, stream>>>(x, nullptr, out);
  }
}

// Round 12
// 172.587 us; speedup vs baseline: 1.1017x; 1.0957x over previous
//
#include <hip/hip_runtime.h>
#include <stdint.h>

typedef __bf16 bf16x8  __attribute__((ext_vector_type(8)));
typedef float  f32x4   __attribute__((ext_vector_type(4)));

#define LOG2E    1.44269504088896340736f
#define SM_SCALE 0.03125f   /* 1/sqrt(1024) */

typedef __attribute__((address_space(1))) const uint32_t gau32;
typedef __attribute__((address_space(3))) uint32_t       lau32;
#define GLD16(g, l) __builtin_amdgcn_global_load_lds((gau32*)(g), (lau32*)(l), 16, 0, 0)

__device__ __forceinline__ uint32_t f2bf(float f) {
  uint32_t u = __builtin_bit_cast(uint32_t, f);
  u += 0x7FFFu + ((u >> 16) & 1u);   // RNE
  return u >> 16;
}
__device__ __forceinline__ uint32_t pk2(float a, float b) {
  return f2bf(a) | (f2bf(b) << 16);
}
__device__ __forceinline__ uint4 pack8(float4 a, float4 b) {
  uint4 r;
  r.x = pk2(a.x, a.y); r.y = pk2(a.z, a.w);
  r.z = pk2(b.x, b.y); r.w = pk2(b.z, b.w);
  return r;
}

// ================= combined prepass (verified r7-r11; at HBM roofline) =================
__global__ __launch_bounds__(256)
void prep_comb(const float* __restrict__ x, uint16_t* __restrict__ vt,
               uint16_t* __restrict__ xf) {
  __shared__ char tl[64 * 144];
  const int t    = threadIdx.x;
  const int blk  = blockIdx.x;
  const int dc   = blk & 15;          // 64-d chunk
  const int kb   = (blk >> 4) & 7;    // 64-key chunk
  const int prob = blk >> 7;          // 0..63
  const int b  = prob >> 4, off = (prob >> 2) & 3, gs = prob & 3;

  const int key = t >> 2, dq = t & 3;
  const float* src = x + ((size_t)(b * 8192 + gs * 2048 + (kb * 64 + key) * 4 + off)) * 1024
                     + dc * 64 + dq * 16;
  float4 f0 = *(const float4*)(src);
  float4 f1 = *(const float4*)(src + 4);
  float4 f2 = *(const float4*)(src + 8);
  float4 f3 = *(const float4*)(src + 12);
  const int swz = (key & 7) << 4;
  *(uint4*)(tl + key * 144 + ((dq * 32) ^ swz))      = pack8(f0, f1);
  *(uint4*)(tl + key * 144 + ((dq * 32 + 16) ^ swz)) = pack8(f2, f3);
  __syncthreads();
  // vt (transposed)
  {
    const int d = t >> 2, kq = t & 3;
    uint32_t w[8];
#pragma unroll
    for (int i = 0; i < 8; ++i) {
      int k0 = kq * 16 + 2 * i, k1 = k0 + 1;
      uint32_t a  = *(const uint16_t*)(tl + k0 * 144 + ((2 * d) ^ ((k0 & 7) << 4)));
      uint32_t bb = *(const uint16_t*)(tl + k1 * 144 + ((2 * d) ^ ((k1 & 7) << 4)));
      w[i] = a | (bb << 16);
    }
    uint16_t* dst = vt + ((size_t)(prob * 1024 + dc * 64 + d)) * 512 + kb * 64 + kq * 16;
    *(uint4*)(dst)     = *(uint4*)&w[0];
    *(uint4*)(dst + 8) = *(uint4*)&w[4];
  }
  // xf (fragment-major)
  {
    const int row = t >> 2, p = t & 3;
    const int dcl = p >> 1;
    const int dq8b = (p & 1) * 2;
    const int swz2 = (row & 7) << 4;
    char* fbase = (char*)xf +
        (((size_t)(prob * 32 + kb * 4 + (row >> 4)) * 32) + (dc * 2 + dcl)) * 1024;
#pragma unroll
    for (int i = 0; i < 2; ++i) {
      const int dq8 = dq8b + i;
      uint4 w = *(const uint4*)(tl + row * 144 + ((dcl * 64 + dq8 * 16) ^ swz2));
      *(uint4*)(fbase + ((row & 15) + 16 * dq8) * 16) = w;
    }
  }
}

// ========== main kernel v10: q-tile 128, grid 256 -> HALVED cache traffic ==========
// LDS: Q-half [0,131072): [dcl 0..15][qt 0..7][1024B] (128 KB, staged twice)
//      P' fragment-major [qt 0..7][ks 0..15][lane][16B] aliases [0,131072)
//      red0 @131072 (16w x 128q f32 = 8 KB), red1 @139264. Total 144 KB, 1 block/CU.
#define R9_0 131072
#define R9_1 139264
#define LDS9_BYTES 147456

__global__ __launch_bounds__(1024, 4)
void dilattn9(const char* __restrict__ xf, const char* __restrict__ vt,
              float* __restrict__ out) {
  extern __shared__ char smem[];

  const int tid  = threadIdx.x;
  const int lane = tid & 63;
  const int wid  = tid >> 6;          // 0..15
  const int h    = lane >> 4;
  const int l15  = lane & 15;
  const int lane16 = lane * 16;

  const int blk  = blockIdx.x;        // 256 blocks; XCD class blk&7 serves probs c*8..c*8+7
  const int jj   = blk >> 3;          // 0..31
  const int prob = ((blk & 7) << 3) + (jj >> 2);
  const int q0   = (jj & 3) * 128;
  const int b    = prob >> 4;
  const int off  = (prob >> 2) & 3;
  const int gs   = prob & 3;

  const char* xfp = xf + (size_t)prob * 1048576;
  const int qtile0 = q0 >> 4;                         // 0,8,16,24
  const char* xfA = xfp + (size_t)(2 * wid) * 32768 + lane16;   // wave's 2 ktiles (32 keys)

  f32x4 S[2][8];
#pragma unroll
  for (int i = 0; i < 2; ++i)
#pragma unroll
    for (int j = 0; j < 8; ++j) S[i][j] = (f32x4){0.f, 0.f, 0.f, 0.f};

  // ===== phase 1: S = K Q^T; Q (128 rows) staged in two 512-d halves =====
#pragma unroll 1
  for (int half = 0; half < 2; ++half) {
#pragma unroll
    for (int i = 0; i < 8; ++i) {                     // stage 128 KB: 16 waves x 8 cells
      const int c_ = wid * 8 + i;
      const int dcl = c_ >> 3, qt = c_ & 7;
      GLD16(xfp + ((size_t)(qtile0 + qt) * 32 + (half * 16 + dcl)) * 1024 + lane16,
            smem + dcl * 8192 + qt * 1024);
    }
    __syncthreads();                                  // half staged
#pragma unroll
    for (int dc = 0; dc < 16; ++dc) {
      const int dca = half * 16 + dc;
      bf16x8 a0 = *(const bf16x8*)(xfA + dca * 1024);
      bf16x8 a1 = *(const bf16x8*)(xfA + 32768 + dca * 1024);
      const char* qb = smem + dc * 8192 + lane16;
      bf16x8 bq[8];
#pragma unroll
      for (int qt = 0; qt < 8; ++qt)
        bq[qt] = *(const bf16x8*)(qb + qt * 1024);
      __builtin_amdgcn_s_setprio(1);
#pragma unroll
      for (int qt = 0; qt < 8; ++qt) {
        S[0][qt] = __builtin_amdgcn_mfma_f32_16x16x32_bf16(a0, bq[qt], S[0][qt], 0, 0, 0);
        S[1][qt] = __builtin_amdgcn_mfma_f32_16x16x32_bf16(a1, bq[qt], S[1][qt], 0, 0, 0);
      }
      __builtin_amdgcn_s_setprio(0);
    }
    __syncthreads();                                  // all waves done reading this half
  }

  // ===== phase 2: exact softmax over 512 keys for 128 q-rows =====
  float mq[8], sq[8], rinv[8];
#pragma unroll
  for (int qt = 0; qt < 8; ++qt) {
    float m = S[0][qt][0];
#pragma unroll
    for (int kt = 0; kt < 2; ++kt)
#pragma unroll
      for (int r = 0; r < 4; ++r) m = fmaxf(m, S[kt][qt][r]);
    m = fmaxf(m, __shfl_xor(m, 16, 64));
    m = fmaxf(m, __shfl_xor(m, 32, 64));
    mq[qt] = m;
  }
  if (h == 0) {
#pragma unroll
    for (int qt = 0; qt < 8; ++qt)
      *(float*)(smem + R9_0 + (wid * 128 + qt * 16 + l15) * 4) = mq[qt];
  }
  __syncthreads();                                    // B1
#pragma unroll
  for (int qt = 0; qt < 8; ++qt) {
    float m = -3e38f;
#pragma unroll
    for (int w = 0; w < 16; ++w)
      m = fmaxf(m, *(const float*)(smem + R9_0 + (w * 128 + qt * 16 + l15) * 4));
    mq[qt] = m * SM_SCALE;
    sq[qt] = 0.f;
  }
#pragma unroll
  for (int kt = 0; kt < 2; ++kt)
#pragma unroll
    for (int qt = 0; qt < 8; ++qt)
#pragma unroll
      for (int r = 0; r < 4; ++r) {
        float v = exp2f((S[kt][qt][r] * SM_SCALE - mq[qt]) * LOG2E);
        S[kt][qt][r] = v;
        sq[qt] += v;
      }
#pragma unroll
  for (int qt = 0; qt < 8; ++qt) {
    sq[qt] += __shfl_xor(sq[qt], 16, 64);
    sq[qt] += __shfl_xor(sq[qt], 32, 64);
  }
  if (h == 0) {
#pragma unroll
    for (int qt = 0; qt < 8; ++qt)
      *(float*)(smem + R9_1 + (wid * 128 + qt * 16 + l15) * 4) = sq[qt];
  }
  __syncthreads();                                    // B2 (Q-frag reads all done)
#pragma unroll
  for (int qt = 0; qt < 8; ++qt) {
    float l = 0.f;
#pragma unroll
    for (int w = 0; w < 16; ++w)
      l += *(const float*)(smem + R9_1 + (w * 128 + qt * 16 + l15) * 4);
    rinv[qt] = 0.25f / l;                            // fold denom and /r=4 into P
  }
  // P' write, fragment-major (r9-verified formula, qt extended to 8):
  // slot lane' = l15 + 16*(2*kt + (h>>1)); byte 8*(h&1); bijective per (qt,wid) KB
#pragma unroll
  for (int kt = 0; kt < 2; ++kt)
#pragma unroll
    for (int qt = 0; qt < 8; ++qt) {
      uint2 w2;
      w2.x = pk2(S[kt][qt][0] * rinv[qt], S[kt][qt][1] * rinv[qt]);
      w2.y = pk2(S[kt][qt][2] * rinv[qt], S[kt][qt][3] * rinv[qt]);
      *(uint2*)(smem + qt * 16384 + wid * 1024 +
                (l15 + 16 * (2 * kt + (h >> 1))) * 16 + 8 * (h & 1)) = w2;
    }
  __syncthreads();                                    // B3: P' ready

  // ===== phase 3: O = P V; two 512-d passes, wave owns 32-d slice; vt read ONCE =====
#pragma unroll 1
  for (int p = 0; p < 2; ++p) {
    const int dbase = p * 512 + 32 * wid;
    f32x4 acc[2][8];
#pragma unroll
    for (int i = 0; i < 2; ++i)
#pragma unroll
      for (int j = 0; j < 8; ++j) acc[i][j] = (f32x4){0.f, 0.f, 0.f, 0.f};

    const char* vtW = vt + (size_t)prob * 1048576 + (size_t)(dbase + l15) * 1024 + 16 * h;
#pragma unroll 1
    for (int ks = 0; ks < 16; ++ks) {
      bf16x8 pa[8];
#pragma unroll
      for (int qt = 0; qt < 8; ++qt)
        pa[qt] = *(const bf16x8*)(smem + qt * 16384 + ks * 1024 + lane16);
      bf16x8 v0 = *(const bf16x8*)(vtW + ks * 64);
      bf16x8 v1 = *(const bf16x8*)(vtW + 16384 + ks * 64);
      __builtin_amdgcn_s_setprio(1);
#pragma unroll
      for (int qt = 0; qt < 8; ++qt) {
        acc[0][qt] = __builtin_amdgcn_mfma_f32_16x16x32_bf16(pa[qt], v0, acc[0][qt], 0, 0, 0);
        acc[1][qt] = __builtin_amdgcn_mfma_f32_16x16x32_bf16(pa[qt], v1, acc[1][qt], 0, 0, 0);
      }
      __builtin_amdgcn_s_setprio(0);
    }
    float* outW = out + ((size_t)(b * 8192 + gs * 2048 + (q0 + 4 * h) * 4 + off)) * 1024
                  + dbase + l15;
#pragma unroll
    for (int cd = 0; cd < 2; ++cd)
#pragma unroll
      for (int qt = 0; qt < 8; ++qt)
#pragma unroll
        for (int r = 0; r < 4; ++r)
          outW[(size_t)((16 * qt + r) * 4) * 1024 + cd * 16] = acc[cd][qt][r];
  }
}

// ======================================================================
// ============ fallback path (round-4, verified PASS) ==================
#define KP_OFF 0
#define Q_OFF  65536
#define RED0   65536
#define RED1   67584
#define LDS_BYTES 73728

__global__ __launch_bounds__(256)
void vt_prepass(const float* __restrict__ x, uint16_t* __restrict__ vt) {
  __shared__ char tl[64 * 144];
  const int t    = threadIdx.x;
  const int blk  = blockIdx.x;
  const int dc   = blk & 15;
  const int kb   = (blk >> 4) & 7;
  const int prob = blk >> 7;
  const int b  = prob >> 4, off = (prob >> 2) & 3, gs = prob & 3;

  const int key = t >> 2, dq = t & 3;
  const float* src = x + ((size_t)(b * 8192 + gs * 2048 + (kb * 64 + key) * 4 + off)) * 1024
                     + dc * 64 + dq * 16;
  float4 f0 = *(const float4*)(src);
  float4 f1 = *(const float4*)(src + 4);
  float4 f2 = *(const float4*)(src + 8);
  float4 f3 = *(const float4*)(src + 12);
  const int swz = (key & 7) << 4;
  *(uint4*)(tl + key * 144 + ((dq * 32) ^ swz))      = pack8(f0, f1);
  *(uint4*)(tl + key * 144 + ((dq * 32 + 16) ^ swz)) = pack8(f2, f3);
  __syncthreads();
  const int d = t >> 2, kq = t & 3;
  uint32_t w[8];
#pragma unroll
  for (int i = 0; i < 8; ++i) {
    int k0 = kq * 16 + 2 * i, k1 = k0 + 1;
    uint32_t a  = *(const uint16_t*)(tl + k0 * 144 + ((2 * d) ^ ((k0 & 7) << 4)));
    uint32_t bb = *(const uint16_t*)(tl + k1 * 144 + ((2 * d) ^ ((k1 & 7) << 4)));
    w[i] = a | (bb << 16);
  }
  uint16_t* dst = vt + ((size_t)(prob * 1024 + dc * 64 + d)) * 512 + kb * 64 + kq * 16;
  *(uint4*)(dst)     = *(uint4*)&w[0];
  *(uint4*)(dst + 8) = *(uint4*)&w[4];
}

template <int USE_VT>
__global__ __launch_bounds__(512, 2)
void dilattn2(const float* __restrict__ x, const uint16_t* __restrict__ vt,
              float* __restrict__ out) {
  extern __shared__ char smem[];

  const int tid  = threadIdx.x;
  const int lane = tid & 63;
  const int wid  = tid >> 6;
  const int h    = lane >> 4;
  const int l15  = lane & 15;
  const int psw  = (l15 & 7) << 4;

  const int blk  = blockIdx.x;
  const int prob = blk >> 3;
  const int q0   = (blk & 7) * 64;
  const int b    = prob >> 4;
  const int off  = (prob >> 2) & 3;
  const int gs   = prob & 3;

  const float* xb = x + (size_t)b * (8192u * 1024u);

  const int srow = tid >> 3;
  const int sg   = tid & 7;
  const float* gK = xb + (size_t)(gs * 2048 + srow * 4 + off) * 1024 + sg * 8;
  const float* gQ = xb + (size_t)(gs * 2048 + (q0 + srow) * 4 + off) * 1024 + sg * 8;
  const int kWr = srow * 128 + ((sg * 16) ^ ((srow & 7) << 4));
  const int qWr = Q_OFF + kWr;

  const int akR = (64 * wid + l15) * 128;
  const int bqR = Q_OFF + l15 * 128;
  const int fb0 = (16 * h) ^ psw;

  f32x4 S[4][4];
#pragma unroll
  for (int i = 0; i < 4; ++i)
#pragma unroll
    for (int j = 0; j < 4; ++j) S[i][j] = (f32x4){0.f, 0.f, 0.f, 0.f};

  float4 kp[16], qp[2];
#pragma unroll
  for (int j = 0; j < 8; ++j) {
    const float* p = gK + (size_t)j * 262144;
    kp[2 * j]     = *(const float4*)(p);
    kp[2 * j + 1] = *(const float4*)(p + 4);
  }
  qp[0] = *(const float4*)(gQ);
  qp[1] = *(const float4*)(gQ + 4);

#pragma unroll 1
  for (int dc = 0; dc < 16; ++dc) {
#pragma unroll
    for (int j = 0; j < 8; ++j)
      *(uint4*)(smem + KP_OFF + kWr + j * 8192) = pack8(kp[2 * j], kp[2 * j + 1]);
    *(uint4*)(smem + qWr) = pack8(qp[0], qp[1]);
    if (dc < 15) {
      const int doff = (dc + 1) * 64;
#pragma unroll
      for (int j = 0; j < 8; ++j) {
        const float* p = gK + (size_t)j * 262144 + doff;
        kp[2 * j]     = *(const float4*)(p);
        kp[2 * j + 1] = *(const float4*)(p + 4);
      }
      qp[0] = *(const float4*)(gQ + doff);
      qp[1] = *(const float4*)(gQ + doff + 4);
    }
    __syncthreads();
#pragma unroll
    for (int s = 0; s < 2; ++s) {
      const int fb = fb0 ^ (s << 6);
      bf16x8 aK[4], bq[4];
#pragma unroll
      for (int kt = 0; kt < 4; ++kt)
        aK[kt] = *(const bf16x8*)(smem + akR + kt * 2048 + fb);
#pragma unroll
      for (int qt = 0; qt < 4; ++qt)
        bq[qt] = *(const bf16x8*)(smem + bqR + qt * 2048 + fb);
#pragma unroll
      for (int kt = 0; kt < 4; ++kt)
#pragma unroll
        for (int qt = 0; qt < 4; ++qt)
          S[kt][qt] = __builtin_amdgcn_mfma_f32_16x16x32_bf16(aK[kt], bq[qt], S[kt][qt], 0, 0, 0);
    }
    __syncthreads();
  }

  float mq[4], sq[4], rinv[4];
#pragma unroll
  for (int qt = 0; qt < 4; ++qt) {
    float m = S[0][qt][0];
#pragma unroll
    for (int kt = 0; kt < 4; ++kt)
#pragma unroll
      for (int r = 0; r < 4; ++r) m = fmaxf(m, S[kt][qt][r]);
    m = fmaxf(m, __shfl_xor(m, 16, 64));
    m = fmaxf(m, __shfl_xor(m, 32, 64));
    mq[qt] = m;
  }
  if (h == 0) {
#pragma unroll
    for (int qt = 0; qt < 4; ++qt)
      *(float*)(smem + RED0 + (wid * 64 + 16 * qt + l15) * 4) = mq[qt];
  }
  __syncthreads();
#pragma unroll
  for (int qt = 0; qt < 4; ++qt) {
    float m = -3e38f;
#pragma unroll
    for (int w = 0; w < 8; ++w)
      m = fmaxf(m, *(const float*)(smem + RED0 + (w * 64 + 16 * qt + l15) * 4));
    mq[qt] = m * SM_SCALE;
    sq[qt] = 0.f;
  }
#pragma unroll
  for (int kt = 0; kt < 4; ++kt)
#pragma unroll
    for (int qt = 0; qt < 4; ++qt)
#pragma unroll
      for (int r = 0; r < 4; ++r) {
        float v = exp2f((S[kt][qt][r] * SM_SCALE - mq[qt]) * LOG2E);
        S[kt][qt][r] = v;
        sq[qt] += v;
      }
#pragma unroll
  for (int qt = 0; qt < 4; ++qt) {
    sq[qt] += __shfl_xor(sq[qt], 16, 64);
    sq[qt] += __shfl_xor(sq[qt], 32, 64);
  }
  if (h == 0) {
#pragma unroll
    for (int qt = 0; qt < 4; ++qt)
      *(float*)(smem + RED1 + (wid * 64 + 16 * qt + l15) * 4) = sq[qt];
  }
  __syncthreads();
#pragma unroll
  for (int qt = 0; qt < 4; ++qt) {
    float l = 0.f;
#pragma unroll
    for (int w = 0; w < 8; ++w)
      l += *(const float*)(smem + RED1 + (w * 64 + 16 * qt + l15) * 4);
    rinv[qt] = 0.25f / l;
  }
#pragma unroll
  for (int kt = 0; kt < 4; ++kt)
#pragma unroll
    for (int qt = 0; qt < 4; ++qt) {
      uint2 w2;
      w2.x = pk2(S[kt][qt][0] * rinv[qt], S[kt][qt][1] * rinv[qt]);
      w2.y = pk2(S[kt][qt][2] * rinv[qt], S[kt][qt][3] * rinv[qt]);
      *(uint2*)(smem + KP_OFF + (16 * qt + l15) * 1024 +
                ((128 * wid + 32 * kt + 8 * h) ^ psw)) = w2;
    }
  __syncthreads();

  f32x4 acc[8][4];
#pragma unroll
  for (int i = 0; i < 8; ++i)
#pragma unroll
    for (int j = 0; j < 4; ++j) acc[i][j] = (f32x4){0.f, 0.f, 0.f, 0.f};

  const uint16_t* vtW = nullptr;
  if constexpr (USE_VT)
    vtW = vt + ((size_t)(prob * 1024 + 128 * wid + l15)) * 512 + 8 * h;

#pragma unroll 1
  for (int ks = 0; ks < 16; ++ks) {
    bf16x8 pa[4];
#pragma unroll
    for (int qt = 0; qt < 4; ++qt)
      pa[qt] = *(const bf16x8*)(smem + KP_OFF + (16 * qt + l15) * 1024 +
                                ((64 * ks + 16 * h) ^ psw));
#pragma unroll
    for (int cd = 0; cd < 8; ++cd) {
      bf16x8 v;
      if constexpr (USE_VT) {
        v = *(const bf16x8*)(vtW + (size_t)((cd >> 2) * 64 + (cd & 3) * 16) * 512 + 32 * ks);
      } else {
        const int d = 128 * wid + (cd >> 2) * 64 + (cd & 3) * 16 + l15;
        union { bf16x8 v; uint16_t u[8]; } a0;
#pragma unroll
        for (int jj = 0; jj < 8; ++jj) {
          int key = 32 * ks + 8 * h + jj;
          a0.u[jj] = (uint16_t)f2bf(xb[(size_t)(gs * 2048 + key * 4 + off) * 1024 + d]);
        }
        v = a0.v;
      }
#pragma unroll
      for (int qt = 0; qt < 4; ++qt)
        acc[cd][qt] = __builtin_amdgcn_mfma_f32_16x16x32_bf16(pa[qt], v, acc[cd][qt], 0, 0, 0);
    }
  }

#pragma unroll
  for (int cd = 0; cd < 8; ++cd) {
    const int d = 128 * wid + (cd >> 2) * 64 + (cd & 3) * 16 + l15;
#pragma unroll
    for (int qt = 0; qt < 4; ++qt)
#pragma unroll
      for (int r = 0; r < 4; ++r) {
        const int qq = q0 + 16 * qt + 4 * h + r;
        out[((size_t)(b * 8192 + gs * 2048 + qq * 4 + off)) * 1024 + d] = acc[cd][qt][r];
      }
  }
}

extern "C" void kernel_launch(void* const* d_in, const int* in_sizes, int n_in,
                              void* d_out, int out_size, void* d_ws, size_t ws_size,
                              hipStream_t stream) {
  const float* x = (const float*)d_in[0];
  float* out = (float*)d_out;
  (void)in_sizes; (void)n_in; (void)out_size;
  const size_t vt_bytes = 64ull * 1024 * 512 * 2;   // 64 MiB
  const size_t xf_bytes = 64ull * 1024 * 1024;      // 64 MiB
  if (ws_size >= vt_bytes + xf_bytes) {
    uint16_t* vtp = (uint16_t*)d_ws;
    uint16_t* xfp = (uint16_t*)((char*)d_ws + vt_bytes);
    hipFuncSetAttribute(reinterpret_cast<const void*>(dilattn9),
                        hipFuncAttributeMaxDynamicSharedMemorySize, LDS9_BYTES);
    prep_comb<<<8192, 256, 0, stream>>>(x, vtp, xfp);
    dilattn9<<<256, 1024, LDS9_BYTES, stream>>>((const char*)xfp, (const char*)vtp, out);
  } else if (ws_size >= vt_bytes) {
    uint16_t* vtp = (uint16_t*)d_ws;
    hipFuncSetAttribute(reinterpret_cast<const void*>(dilattn2<1>),
                        hipFuncAttributeMaxDynamicSharedMemorySize, LDS_BYTES);
    vt_prepass<<<8192, 256, 0, stream>>>(x, vtp);
    dilattn2<1><<<512, 512, LDS_BYTES, stream>>>(x, vtp, out);
  } else {
    hipFuncSetAttribute(reinterpret_cast<const void*>(dilattn2<0>),
                        hipFuncAttributeMaxDynamicSharedMemorySize, LDS_BYTES);
    dilattn2<0><<<512, 512, LDS_BYTES, stream>>>(x, nullptr, out);
  }
}

// Round 13
// 170.909 us; speedup vs baseline: 1.1125x; 1.0098x over previous
//
#include <hip/hip_runtime.h>
#include <stdint.h>

typedef __bf16 bf16x8  __attribute__((ext_vector_type(8)));
typedef float  f32x4   __attribute__((ext_vector_type(4)));

#define LOG2E    1.44269504088896340736f
#define SM_SCALE 0.03125f   /* 1/sqrt(1024) */

typedef __attribute__((address_space(1))) const uint32_t gau32;
typedef __attribute__((address_space(3))) uint32_t       lau32;
#define GLD16(g, l) __builtin_amdgcn_global_load_lds((gau32*)(g), (lau32*)(l), 16, 0, 0)
#define VMW2() asm volatile("s_waitcnt vmcnt(2)" ::: "memory")
#define VMW0() asm volatile("s_waitcnt vmcnt(0)" ::: "memory")
#define LGKM_BAR() do { asm volatile("s_waitcnt lgkmcnt(0)" ::: "memory"); \
  __builtin_amdgcn_s_barrier(); asm volatile("" ::: "memory"); } while (0)

__device__ __forceinline__ uint32_t f2bf(float f) {
  uint32_t u = __builtin_bit_cast(uint32_t, f);
  u += 0x7FFFu + ((u >> 16) & 1u);   // RNE
  return u >> 16;
}
__device__ __forceinline__ uint32_t pk2(float a, float b) {
  return f2bf(a) | (f2bf(b) << 16);
}
__device__ __forceinline__ uint4 pack8(float4 a, float4 b) {
  uint4 r;
  r.x = pk2(a.x, a.y); r.y = pk2(a.z, a.w);
  r.z = pk2(b.x, b.y); r.w = pk2(b.z, b.w);
  return r;
}

// ================= combined prepass (verified r7-r12; at HBM roofline) =================
__global__ __launch_bounds__(256)
void prep_comb(const float* __restrict__ x, uint16_t* __restrict__ vt,
               uint16_t* __restrict__ xf) {
  __shared__ char tl[64 * 144];
  const int t    = threadIdx.x;
  const int blk  = blockIdx.x;
  const int dc   = blk & 15;          // 64-d chunk
  const int kb   = (blk >> 4) & 7;    // 64-key chunk
  const int prob = blk >> 7;          // 0..63
  const int b  = prob >> 4, off = (prob >> 2) & 3, gs = prob & 3;

  const int key = t >> 2, dq = t & 3;
  const float* src = x + ((size_t)(b * 8192 + gs * 2048 + (kb * 64 + key) * 4 + off)) * 1024
                     + dc * 64 + dq * 16;
  float4 f0 = *(const float4*)(src);
  float4 f1 = *(const float4*)(src + 4);
  float4 f2 = *(const float4*)(src + 8);
  float4 f3 = *(const float4*)(src + 12);
  const int swz = (key & 7) << 4;
  *(uint4*)(tl + key * 144 + ((dq * 32) ^ swz))      = pack8(f0, f1);
  *(uint4*)(tl + key * 144 + ((dq * 32 + 16) ^ swz)) = pack8(f2, f3);
  __syncthreads();
  // vt (transposed)
  {
    const int d = t >> 2, kq = t & 3;
    uint32_t w[8];
#pragma unroll
    for (int i = 0; i < 8; ++i) {
      int k0 = kq * 16 + 2 * i, k1 = k0 + 1;
      uint32_t a  = *(const uint16_t*)(tl + k0 * 144 + ((2 * d) ^ ((k0 & 7) << 4)));
      uint32_t bb = *(const uint16_t*)(tl + k1 * 144 + ((2 * d) ^ ((k1 & 7) << 4)));
      w[i] = a | (bb << 16);
    }
    uint16_t* dst = vt + ((size_t)(prob * 1024 + dc * 64 + d)) * 512 + kb * 64 + kq * 16;
    *(uint4*)(dst)     = *(uint4*)&w[0];
    *(uint4*)(dst + 8) = *(uint4*)&w[4];
  }
  // xf (fragment-major)
  {
    const int row = t >> 2, p = t & 3;
    const int dcl = p >> 1;
    const int dq8b = (p & 1) * 2;
    const int swz2 = (row & 7) << 4;
    char* fbase = (char*)xf +
        (((size_t)(prob * 32 + kb * 4 + (row >> 4)) * 32) + (dc * 2 + dcl)) * 1024;
#pragma unroll
    for (int i = 0; i < 2; ++i) {
      const int dq8 = dq8b + i;
      uint4 w = *(const uint4*)(tl + row * 144 + ((dcl * 64 + dq8 * 16) ^ swz2));
      *(uint4*)(fbase + ((row & 15) + 16 * dq8) * 16) = w;
    }
  }
}

// ========== main kernel v11: r12 + A-frag LDS ring (counted vmcnt) + V depth-2 ==========
// LDS: phase 1: Q-quarter [0,65536): [dcl 0..7][qt 0..7][1024B];
//               ring [65536,131072): per-wave 4 KB = 2 slots x 2 KB
//      phase 3: P' fragment-major [qt 0..7][ks][lane][16B] aliases [0,131072)
//      red0 @131072, red1 @139264. Total 144 KB, 1 block/CU.
#define RA_0 131072
#define RA_1 139264
#define LDSA_BYTES 147456

__global__ __launch_bounds__(1024, 4)
void dilattn10(const char* __restrict__ xf, const char* __restrict__ vt,
               float* __restrict__ out) {
  extern __shared__ char smem[];

  const int tid  = threadIdx.x;
  const int lane = tid & 63;
  const int wid  = tid >> 6;          // 0..15
  const int h    = lane >> 4;
  const int l15  = lane & 15;
  const int lane16 = lane * 16;

  const int blk  = blockIdx.x;        // 256 blocks; same-prob q-blocks share XCD class
  const int jj   = blk >> 3;          // 0..31
  const int prob = ((blk & 7) << 3) + (jj >> 2);
  const int q0   = (jj & 3) * 128;
  const int b    = prob >> 4;
  const int off  = (prob >> 2) & 3;
  const int gs   = prob & 3;

  const char* xfp = xf + (size_t)prob * 1048576;
  const int qtile0 = q0 >> 4;
  const char* xfA = xfp + (size_t)(2 * wid) * 32768 + lane16;   // wave's 2 ktiles
  char* ring = smem + 65536 + wid * 4096;                        // wave-private 2-slot ring

#define ISSUE_A10(dca, s) do {                                                    \
    GLD16(xfA + (dca) * 1024, ring + (s) * 2048);                                 \
    GLD16(xfA + 32768 + (dca) * 1024, ring + (s) * 2048 + 1024); } while (0)

  f32x4 S[2][8];
#pragma unroll
  for (int i = 0; i < 2; ++i)
#pragma unroll
    for (int j = 0; j < 8; ++j) S[i][j] = (f32x4){0.f, 0.f, 0.f, 0.f};

  // ===== phase 1: S = K Q^T; Q in 4 quarters; A via ring w/ counted vmcnt =====
#pragma unroll 1
  for (int quarter = 0; quarter < 4; ++quarter) {
    // stage Q quarter (64 cells = 16 waves x 4)
#pragma unroll
    for (int i = 0; i < 4; ++i) {
      const int c_ = wid * 4 + i;
      const int dcl = c_ >> 3, qt = c_ & 7;
      GLD16(xfp + ((size_t)(qtile0 + qt) * 32 + (quarter * 8 + dcl)) * 1024 + lane16,
            smem + dcl * 8192 + qt * 1024);
    }
    ISSUE_A10(quarter * 8 + 0, 0);
    ISSUE_A10(quarter * 8 + 1, 1);
    VMW2();                                  // stage(4)+A0 landed; A1 in flight
    __builtin_amdgcn_s_barrier();            // quarter readable by all waves
    asm volatile("" ::: "memory");
#pragma unroll
    for (int dc = 0; dc < 8; ++dc) {
      if (dc >= 1) { if (dc < 7) VMW2(); else VMW0(); }
      const char* av = ring + (dc & 1) * 2048 + lane16;
      bf16x8 a0 = *(const bf16x8*)(av);
      bf16x8 a1 = *(const bf16x8*)(av + 1024);
      const char* qb = smem + dc * 8192 + lane16;
      bf16x8 bq[8];
#pragma unroll
      for (int qt = 0; qt < 8; ++qt)
        bq[qt] = *(const bf16x8*)(qb + qt * 1024);
      __builtin_amdgcn_s_setprio(1);
#pragma unroll
      for (int qt = 0; qt < 8; ++qt) {
        S[0][qt] = __builtin_amdgcn_mfma_f32_16x16x32_bf16(a0, bq[qt], S[0][qt], 0, 0, 0);
        S[1][qt] = __builtin_amdgcn_mfma_f32_16x16x32_bf16(a1, bq[qt], S[1][qt], 0, 0, 0);
      }
      __builtin_amdgcn_s_setprio(0);
      if (dc < 6) ISSUE_A10(quarter * 8 + dc + 2, dc & 1);
    }
    LGKM_BAR();                              // Q-quarter reads done; ring drained (VMW0)
  }

  // ===== phase 2: exact softmax over 512 keys for 128 q-rows (r12-verified) =====
  float mq[8], sq[8], rinv[8];
#pragma unroll
  for (int qt = 0; qt < 8; ++qt) {
    float m = S[0][qt][0];
#pragma unroll
    for (int kt = 0; kt < 2; ++kt)
#pragma unroll
      for (int r = 0; r < 4; ++r) m = fmaxf(m, S[kt][qt][r]);
    m = fmaxf(m, __shfl_xor(m, 16, 64));
    m = fmaxf(m, __shfl_xor(m, 32, 64));
    mq[qt] = m;
  }
  if (h == 0) {
#pragma unroll
    for (int qt = 0; qt < 8; ++qt)
      *(float*)(smem + RA_0 + (wid * 128 + qt * 16 + l15) * 4) = mq[qt];
  }
  __syncthreads();                                    // B1
#pragma unroll
  for (int qt = 0; qt < 8; ++qt) {
    float m = -3e38f;
#pragma unroll
    for (int w = 0; w < 16; ++w)
      m = fmaxf(m, *(const float*)(smem + RA_0 + (w * 128 + qt * 16 + l15) * 4));
    mq[qt] = m * SM_SCALE;
    sq[qt] = 0.f;
  }
#pragma unroll
  for (int kt = 0; kt < 2; ++kt)
#pragma unroll
    for (int qt = 0; qt < 8; ++qt)
#pragma unroll
      for (int r = 0; r < 4; ++r) {
        float v = exp2f((S[kt][qt][r] * SM_SCALE - mq[qt]) * LOG2E);
        S[kt][qt][r] = v;
        sq[qt] += v;
      }
#pragma unroll
  for (int qt = 0; qt < 8; ++qt) {
    sq[qt] += __shfl_xor(sq[qt], 16, 64);
    sq[qt] += __shfl_xor(sq[qt], 32, 64);
  }
  if (h == 0) {
#pragma unroll
    for (int qt = 0; qt < 8; ++qt)
      *(float*)(smem + RA_1 + (wid * 128 + qt * 16 + l15) * 4) = sq[qt];
  }
  __syncthreads();                                    // B2
#pragma unroll
  for (int qt = 0; qt < 8; ++qt) {
    float l = 0.f;
#pragma unroll
    for (int w = 0; w < 16; ++w)
      l += *(const float*)(smem + RA_1 + (w * 128 + qt * 16 + l15) * 4);
    rinv[qt] = 0.25f / l;                            // fold denom and /r=4 into P
  }
  // P' write, fragment-major (r12-verified)
#pragma unroll
  for (int kt = 0; kt < 2; ++kt)
#pragma unroll
    for (int qt = 0; qt < 8; ++qt) {
      uint2 w2;
      w2.x = pk2(S[kt][qt][0] * rinv[qt], S[kt][qt][1] * rinv[qt]);
      w2.y = pk2(S[kt][qt][2] * rinv[qt], S[kt][qt][3] * rinv[qt]);
      *(uint2*)(smem + qt * 16384 + wid * 1024 +
                (l15 + 16 * (2 * kt + (h >> 1))) * 16 + 8 * (h & 1)) = w2;
    }
  __syncthreads();                                    // B3: P' ready

  // ===== phase 3: O = P V; two 512-d passes; V depth-2; pa 2-at-a-time =====
#pragma unroll 1
  for (int p = 0; p < 2; ++p) {
    const int dbase = p * 512 + 32 * wid;
    f32x4 acc[2][8];
#pragma unroll
    for (int i = 0; i < 2; ++i)
#pragma unroll
      for (int j = 0; j < 8; ++j) acc[i][j] = (f32x4){0.f, 0.f, 0.f, 0.f};

    const char* vtW = vt + (size_t)prob * 1048576 + (size_t)(dbase + l15) * 1024 + 16 * h;
    bf16x8 vc0 = *(const bf16x8*)(vtW);
    bf16x8 vc1 = *(const bf16x8*)(vtW + 16384);
#pragma unroll 1
    for (int ks = 0; ks < 16; ++ks) {
      bf16x8 vn0, vn1;
      if (ks < 15) {
        vn0 = *(const bf16x8*)(vtW + (ks + 1) * 64);
        vn1 = *(const bf16x8*)(vtW + 16384 + (ks + 1) * 64);
      }
      __builtin_amdgcn_s_setprio(1);
#pragma unroll
      for (int qp = 0; qp < 4; ++qp) {
        bf16x8 pa0 = *(const bf16x8*)(smem + (2 * qp) * 16384 + ks * 1024 + lane16);
        bf16x8 pa1 = *(const bf16x8*)(smem + (2 * qp + 1) * 16384 + ks * 1024 + lane16);
        acc[0][2 * qp]     = __builtin_amdgcn_mfma_f32_16x16x32_bf16(pa0, vc0, acc[0][2 * qp], 0, 0, 0);
        acc[1][2 * qp]     = __builtin_amdgcn_mfma_f32_16x16x32_bf16(pa0, vc1, acc[1][2 * qp], 0, 0, 0);
        acc[0][2 * qp + 1] = __builtin_amdgcn_mfma_f32_16x16x32_bf16(pa1, vc0, acc[0][2 * qp + 1], 0, 0, 0);
        acc[1][2 * qp + 1] = __builtin_amdgcn_mfma_f32_16x16x32_bf16(pa1, vc1, acc[1][2 * qp + 1], 0, 0, 0);
      }
      __builtin_amdgcn_s_setprio(0);
      if (ks < 15) { vc0 = vn0; vc1 = vn1; }
    }
    float* outW = out + ((size_t)(b * 8192 + gs * 2048 + (q0 + 4 * h) * 4 + off)) * 1024
                  + dbase + l15;
#pragma unroll
    for (int cd = 0; cd < 2; ++cd)
#pragma unroll
      for (int qt = 0; qt < 8; ++qt)
#pragma unroll
        for (int r = 0; r < 4; ++r)
          outW[(size_t)((16 * qt + r) * 4) * 1024 + cd * 16] = acc[cd][qt][r];
  }
#undef ISSUE_A10
}

// ======================================================================
// ============ fallback path (round-4, verified PASS) ==================
#define KP_OFF 0
#define Q_OFF  65536
#define RED0   65536
#define RED1   67584
#define LDS_BYTES 73728

__global__ __launch_bounds__(256)
void vt_prepass(const float* __restrict__ x, uint16_t* __restrict__ vt) {
  __shared__ char tl[64 * 144];
  const int t    = threadIdx.x;
  const int blk  = blockIdx.x;
  const int dc   = blk & 15;
  const int kb   = (blk >> 4) & 7;
  const int prob = blk >> 7;
  const int b  = prob >> 4, off = (prob >> 2) & 3, gs = prob & 3;

  const int key = t >> 2, dq = t & 3;
  const float* src = x + ((size_t)(b * 8192 + gs * 2048 + (kb * 64 + key) * 4 + off)) * 1024
                     + dc * 64 + dq * 16;
  float4 f0 = *(const float4*)(src);
  float4 f1 = *(const float4*)(src + 4);
  float4 f2 = *(const float4*)(src + 8);
  float4 f3 = *(const float4*)(src + 12);
  const int swz = (key & 7) << 4;
  *(uint4*)(tl + key * 144 + ((dq * 32) ^ swz))      = pack8(f0, f1);
  *(uint4*)(tl + key * 144 + ((dq * 32 + 16) ^ swz)) = pack8(f2, f3);
  __syncthreads();
  const int d = t >> 2, kq = t & 3;
  uint32_t w[8];
#pragma unroll
  for (int i = 0; i < 8; ++i) {
    int k0 = kq * 16 + 2 * i, k1 = k0 + 1;
    uint32_t a  = *(const uint16_t*)(tl + k0 * 144 + ((2 * d) ^ ((k0 & 7) << 4)));
    uint32_t bb = *(const uint16_t*)(tl + k1 * 144 + ((2 * d) ^ ((k1 & 7) << 4)));
    w[i] = a | (bb << 16);
  }
  uint16_t* dst = vt + ((size_t)(prob * 1024 + dc * 64 + d)) * 512 + kb * 64 + kq * 16;
  *(uint4*)(dst)     = *(uint4*)&w[0];
  *(uint4*)(dst + 8) = *(uint4*)&w[4];
}

template <int USE_VT>
__global__ __launch_bounds__(512, 2)
void dilattn2(const float* __restrict__ x, const uint16_t* __restrict__ vt,
              float* __restrict__ out) {
  extern __shared__ char smem[];

  const int tid  = threadIdx.x;
  const int lane = tid & 63;
  const int wid  = tid >> 6;
  const int h    = lane >> 4;
  const int l15  = lane & 15;
  const int psw  = (l15 & 7) << 4;

  const int blk  = blockIdx.x;
  const int prob = blk >> 3;
  const int q0   = (blk & 7) * 64;
  const int b    = prob >> 4;
  const int off  = (prob >> 2) & 3;
  const int gs   = prob & 3;

  const float* xb = x + (size_t)b * (8192u * 1024u);

  const int srow = tid >> 3;
  const int sg   = tid & 7;
  const float* gK = xb + (size_t)(gs * 2048 + srow * 4 + off) * 1024 + sg * 8;
  const float* gQ = xb + (size_t)(gs * 2048 + (q0 + srow) * 4 + off) * 1024 + sg * 8;
  const int kWr = srow * 128 + ((sg * 16) ^ ((srow & 7) << 4));
  const int qWr = Q_OFF + kWr;

  const int akR = (64 * wid + l15) * 128;
  const int bqR = Q_OFF + l15 * 128;
  const int fb0 = (16 * h) ^ psw;

  f32x4 S[4][4];
#pragma unroll
  for (int i = 0; i < 4; ++i)
#pragma unroll
    for (int j = 0; j < 4; ++j) S[i][j] = (f32x4){0.f, 0.f, 0.f, 0.f};

  float4 kp[16], qp[2];
#pragma unroll
  for (int j = 0; j < 8; ++j) {
    const float* p = gK + (size_t)j * 262144;
    kp[2 * j]     = *(const float4*)(p);
    kp[2 * j + 1] = *(const float4*)(p + 4);
  }
  qp[0] = *(const float4*)(gQ);
  qp[1] = *(const float4*)(gQ + 4);

#pragma unroll 1
  for (int dc = 0; dc < 16; ++dc) {
#pragma unroll
    for (int j = 0; j < 8; ++j)
      *(uint4*)(smem + KP_OFF + kWr + j * 8192) = pack8(kp[2 * j], kp[2 * j + 1]);
    *(uint4*)(smem + qWr) = pack8(qp[0], qp[1]);
    if (dc < 15) {
      const int doff = (dc + 1) * 64;
#pragma unroll
      for (int j = 0; j < 8; ++j) {
        const float* p = gK + (size_t)j * 262144 + doff;
        kp[2 * j]     = *(const float4*)(p);
        kp[2 * j + 1] = *(const float4*)(p + 4);
      }
      qp[0] = *(const float4*)(gQ + doff);
      qp[1] = *(const float4*)(gQ + doff + 4);
    }
    __syncthreads();
#pragma unroll
    for (int s = 0; s < 2; ++s) {
      const int fb = fb0 ^ (s << 6);
      bf16x8 aK[4], bq[4];
#pragma unroll
      for (int kt = 0; kt < 4; ++kt)
        aK[kt] = *(const bf16x8*)(smem + akR + kt * 2048 + fb);
#pragma unroll
      for (int qt = 0; qt < 4; ++qt)
        bq[qt] = *(const bf16x8*)(smem + bqR + qt * 2048 + fb);
#pragma unroll
      for (int kt = 0; kt < 4; ++kt)
#pragma unroll
        for (int qt = 0; qt < 4; ++qt)
          S[kt][qt] = __builtin_amdgcn_mfma_f32_16x16x32_bf16(aK[kt], bq[qt], S[kt][qt], 0, 0, 0);
    }
    __syncthreads();
  }

  float mq[4], sq[4], rinv[4];
#pragma unroll
  for (int qt = 0; qt < 4; ++qt) {
    float m = S[0][qt][0];
#pragma unroll
    for (int kt = 0; kt < 4; ++kt)
#pragma unroll
      for (int r = 0; r < 4; ++r) m = fmaxf(m, S[kt][qt][r]);
    m = fmaxf(m, __shfl_xor(m, 16, 64));
    m = fmaxf(m, __shfl_xor(m, 32, 64));
    mq[qt] = m;
  }
  if (h == 0) {
#pragma unroll
    for (int qt = 0; qt < 4; ++qt)
      *(float*)(smem + RED0 + (wid * 64 + 16 * qt + l15) * 4) = mq[qt];
  }
  __syncthreads();
#pragma unroll
  for (int qt = 0; qt < 4; ++qt) {
    float m = -3e38f;
#pragma unroll
    for (int w = 0; w < 8; ++w)
      m = fmaxf(m, *(const float*)(smem + RED0 + (w * 64 + 16 * qt + l15) * 4));
    mq[qt] = m * SM_SCALE;
    sq[qt] = 0.f;
  }
#pragma unroll
  for (int kt = 0; kt < 4; ++kt)
#pragma unroll
    for (int qt = 0; qt < 4; ++qt)
#pragma unroll
      for (int r = 0; r < 4; ++r) {
        float v = exp2f((S[kt][qt][r] * SM_SCALE - mq[qt]) * LOG2E);
        S[kt][qt][r] = v;
        sq[qt] += v;
      }
#pragma unroll
  for (int qt = 0; qt < 4; ++qt) {
    sq[qt] += __shfl_xor(sq[qt], 16, 64);
    sq[qt] += __shfl_xor(sq[qt], 32, 64);
  }
  if (h == 0) {
#pragma unroll
    for (int qt = 0; qt < 4; ++qt)
      *(float*)(smem + RED1 + (wid * 64 + 16 * qt + l15) * 4) = sq[qt];
  }
  __syncthreads();
#pragma unroll
  for (int qt = 0; qt < 4; ++qt) {
    float l = 0.f;
#pragma unroll
    for (int w = 0; w < 8; ++w)
      l += *(const float*)(smem + RED1 + (w * 64 + 16 * qt + l15) * 4);
    rinv[qt] = 0.25f / l;
  }
#pragma unroll
  for (int kt = 0; kt < 4; ++kt)
#pragma unroll
    for (int qt = 0; qt < 4; ++qt) {
      uint2 w2;
      w2.x = pk2(S[kt][qt][0] * rinv[qt], S[kt][qt][1] * rinv[qt]);
      w2.y = pk2(S[kt][qt][2] * rinv[qt], S[kt][qt][3] * rinv[qt]);
      *(uint2*)(smem + KP_OFF + (16 * qt + l15) * 1024 +
                ((128 * wid + 32 * kt + 8 * h) ^ psw)) = w2;
    }
  __syncthreads();

  f32x4 acc[8][4];
#pragma unroll
  for (int i = 0; i < 8; ++i)
#pragma unroll
    for (int j = 0; j < 4; ++j) acc[i][j] = (f32x4){0.f, 0.f, 0.f, 0.f};

  const uint16_t* vtW = nullptr;
  if constexpr (USE_VT)
    vtW = vt + ((size_t)(prob * 1024 + 128 * wid + l15)) * 512 + 8 * h;

#pragma unroll 1
  for (int ks = 0; ks < 16; ++ks) {
    bf16x8 pa[4];
#pragma unroll
    for (int qt = 0; qt < 4; ++qt)
      pa[qt] = *(const bf16x8*)(smem + KP_OFF + (16 * qt + l15) * 1024 +
                                ((64 * ks + 16 * h) ^ psw));
#pragma unroll
    for (int cd = 0; cd < 8; ++cd) {
      bf16x8 v;
      if constexpr (USE_VT) {
        v = *(const bf16x8*)(vtW + (size_t)((cd >> 2) * 64 + (cd & 3) * 16) * 512 + 32 * ks);
      } else {
        const int d = 128 * wid + (cd >> 2) * 64 + (cd & 3) * 16 + l15;
        union { bf16x8 v; uint16_t u[8]; } a0;
#pragma unroll
        for (int jj = 0; jj < 8; ++jj) {
          int key = 32 * ks + 8 * h + jj;
          a0.u[jj] = (uint16_t)f2bf(xb[(size_t)(gs * 2048 + key * 4 + off) * 1024 + d]);
        }
        v = a0.v;
      }
#pragma unroll
      for (int qt = 0; qt < 4; ++qt)
        acc[cd][qt] = __builtin_amdgcn_mfma_f32_16x16x32_bf16(pa[qt], v, acc[cd][qt], 0, 0, 0);
    }
  }

#pragma unroll
  for (int cd = 0; cd < 8; ++cd) {
    const int d = 128 * wid + (cd >> 2) * 64 + (cd & 3) * 16 + l15;
#pragma unroll
    for (int qt = 0; qt < 4; ++qt)
#pragma unroll
      for (int r = 0; r < 4; ++r) {
        const int qq = q0 + 16 * qt + 4 * h + r;
        out[((size_t)(b * 8192 + gs * 2048 + qq * 4 + off)) * 1024 + d] = acc[cd][qt][r];
      }
  }
}

extern "C" void kernel_launch(void* const* d_in, const int* in_sizes, int n_in,
                              void* d_out, int out_size, void* d_ws, size_t ws_size,
                              hipStream_t stream) {
  const float* x = (const float*)d_in[0];
  float* out = (float*)d_out;
  (void)in_sizes; (void)n_in; (void)out_size;
  const size_t vt_bytes = 64ull * 1024 * 512 * 2;   // 64 MiB
  const size_t xf_bytes = 64ull * 1024 * 1024;      // 64 MiB
  if (ws_size >= vt_bytes + xf_bytes) {
    uint16_t* vtp = (uint16_t*)d_ws;
    uint16_t* xfp = (uint16_t*)((char*)d_ws + vt_bytes);
    hipFuncSetAttribute(reinterpret_cast<const void*>(dilattn10),
                        hipFuncAttributeMaxDynamicSharedMemorySize, LDSA_BYTES);
    prep_comb<<<8192, 256, 0, stream>>>(x, vtp, xfp);
    dilattn10<<<256, 1024, LDSA_BYTES, stream>>>((const char*)xfp, (const char*)vtp, out);
  } else if (ws_size >= vt_bytes) {
    uint16_t* vtp = (uint16_t*)d_ws;
    hipFuncSetAttribute(reinterpret_cast<const void*>(dilattn2<1>),
                        hipFuncAttributeMaxDynamicSharedMemorySize, LDS_BYTES);
    vt_prepass<<<8192, 256, 0, stream>>>(x, vtp);
    dilattn2<1><<<512, 512, LDS_BYTES, stream>>>(x, vtp, out);
  } else {
    hipFuncSetAttribute(reinterpret_cast<const void*>(dilattn2<0>),
                        hipFuncAttributeMaxDynamicSharedMemorySize, LDS_BYTES);
    dilattn2<0><<<512, 512, LDS_BYTES, stream>>>(x, nullptr, out);
  }
}